// Round 1
// baseline (1107.559 us; speedup 1.0000x reference)
//
#include <hip/hip_runtime.h>

#define N_NODES 100000
#define N_EDGES 1600000
#define IN_DIM  128
#define HID     64
#define MLP_HID 256
#define OUT_DIM 128
#define SCAN_NB 98   // ceil(100000/1024)

// ---------------- graph build ----------------

__global__ void k_count(const int* __restrict__ dst, int* __restrict__ counts) {
  int e = blockIdx.x * 256 + threadIdx.x;
  if (e < N_EDGES) atomicAdd(&counts[dst[e]], 1);
}

__global__ void k_dinv(const int* __restrict__ counts, float* __restrict__ dinv) {
  int i = blockIdx.x * 256 + threadIdx.x;
  if (i < N_NODES) dinv[i] = rsqrtf((float)(counts[i] + 1));  // +1 self-loop, always > 0
}

__global__ void k_blocksums(const int* __restrict__ counts, int* __restrict__ bsums) {
  __shared__ int sd[256];
  int b = blockIdx.x, t = threadIdx.x;
  int i0 = b * 1024 + t * 4;
  int s = 0;
  #pragma unroll
  for (int i = 0; i < 4; i++) { int idx = i0 + i; if (idx < N_NODES) s += counts[idx]; }
  sd[t] = s;
  __syncthreads();
  for (int off = 128; off > 0; off >>= 1) {
    if (t < off) sd[t] += sd[t + off];
    __syncthreads();
  }
  if (t == 0) bsums[b] = sd[0];
}

__global__ void k_scan_bsums(const int* __restrict__ bsums, int* __restrict__ bbase) {
  if (threadIdx.x == 0 && blockIdx.x == 0) {
    int run = 0;
    #pragma unroll 1
    for (int b = 0; b < SCAN_NB; b++) { bbase[b] = run; run += bsums[b]; }
  }
}

__global__ void k_offsets(const int* __restrict__ counts, const int* __restrict__ bbase,
                          int* __restrict__ offsets) {
  __shared__ int ts[256];
  int b = blockIdx.x, t = threadIdx.x;
  int i0 = b * 1024 + t * 4;
  int loc[4];
  #pragma unroll
  for (int i = 0; i < 4; i++) { int idx = i0 + i; loc[i] = (idx < N_NODES) ? counts[idx] : 0; }
  int my = loc[0] + loc[1] + loc[2] + loc[3];
  ts[t] = my;
  __syncthreads();
  int v = my;
  for (int off = 1; off < 256; off <<= 1) {
    int y = (t >= off) ? ts[t - off] : 0;
    __syncthreads();
    v += y;
    ts[t] = v;
    __syncthreads();
  }
  int run = v - my + bbase[b];  // exclusive base for this thread's 4 elements
  #pragma unroll
  for (int i = 0; i < 4; i++) {
    int idx = i0 + i;
    if (idx < N_NODES) offsets[idx] = run;
    run += loc[i];
  }
  if (b == 0 && t == 0) offsets[N_NODES] = N_EDGES;
}

__global__ void k_fill(const int* __restrict__ src, const int* __restrict__ dst,
                       const int* __restrict__ offsets, int* __restrict__ cursor,
                       int* __restrict__ csr_src) {
  int e = blockIdx.x * 256 + threadIdx.x;
  if (e < N_EDGES) {
    int d = dst[e];
    int pos = offsets[d] + atomicAdd(&cursor[d], 1);
    csr_src[pos] = src[e];
  }
}

// ---------------- conv linear: out[n][0:64] = X[n][0:K] @ W[K][64] ----------------
// 256 threads, 32 nodes/block (exact: 100000 = 3125*32). thread: node = t>>3, j-set = (t&7)*8..+8

template<int K>
__global__ __launch_bounds__(256)
void k_gemm64(const float* __restrict__ X, const float* __restrict__ W,
              float* __restrict__ out) {
  __shared__ float sx[32][K + 4];   // +4 pad: bank stride 4 -> conflict-free n-major reads
  int t = threadIdx.x;
  int base = blockIdx.x * 32;
  const int tot4 = 32 * K / 4;
  for (int i = t; i < tot4; i += 256) {
    int f = i * 4;
    int r = f / K, c = f % K;
    *(float4*)&sx[r][c] = *(const float4*)(X + (size_t)(base + r) * K + c);
  }
  __syncthreads();
  const int jt = t & 7;
  const int n  = t >> 3;
  float acc[8];
  #pragma unroll
  for (int j = 0; j < 8; j++) acc[j] = 0.f;
  for (int k0 = 0; k0 < K; k0 += 8) {
    float wr[8][8];
    #pragma unroll
    for (int kk = 0; kk < 8; kk++) {
      const float4* wp = (const float4*)(W + (size_t)(k0 + kk) * 64 + jt * 8);
      float4 w0 = wp[0], w1 = wp[1];
      wr[kk][0] = w0.x; wr[kk][1] = w0.y; wr[kk][2] = w0.z; wr[kk][3] = w0.w;
      wr[kk][4] = w1.x; wr[kk][5] = w1.y; wr[kk][6] = w1.z; wr[kk][7] = w1.w;
    }
    #pragma unroll
    for (int kk = 0; kk < 8; kk++) {
      float xv = sx[n][k0 + kk];
      #pragma unroll
      for (int jj = 0; jj < 8; jj++) acc[jj] += xv * wr[kk][jj];
    }
  }
  float* op = out + (size_t)(base + n) * 64 + jt * 8;
  *(float4*)op       = make_float4(acc[0], acc[1], acc[2], acc[3]);
  *(float4*)(op + 4) = make_float4(acc[4], acc[5], acc[6], acc[7]);
}

// ---------------- aggregation: one wave per node, lane = channel (HID=64) ----------------

__global__ __launch_bounds__(256)
void k_aggregate(const float* __restrict__ h, const int* __restrict__ offsets,
                 const int* __restrict__ csr_src, const float* __restrict__ dinv,
                 const float* __restrict__ bias, float* __restrict__ out) {
  int lane = threadIdx.x & 63;
  int wid = (blockIdx.x * 256 + threadIdx.x) >> 6;
  int nw = (gridDim.x * 256) >> 6;
  float bv = bias[lane];
  for (int v = wid; v < N_NODES; v += nw) {
    float dv = dinv[v];
    float acc = h[(size_t)v * 64 + lane] * (dv * dv);   // self-loop
    int e1 = offsets[v + 1];
    for (int e = offsets[v]; e < e1; e++) {
      int s = csr_src[e];
      acc += h[(size_t)s * 64 + lane] * (dinv[s] * dv);
    }
    float r = acc + bv;
    out[(size_t)v * 64 + lane] = r > 0.f ? r : 0.f;     // fused bias + ReLU
  }
}

// ---------------- fused MLP: 64 -> 256 -> 256 -> 128, all activations in LDS ----------------
// 256 threads, 32 nodes/block. thread: jt = t&31 (8 cols in layers 1/2, 4 in layer 3),
// ng = t>>5 -> nodes ng*4..ng*4+3. Weight chunks (8k x 8j) staged in registers from L1/L2.

__global__ __launch_bounds__(256, 2)
void k_mlp(const float* __restrict__ X,
           const float* __restrict__ Wf1, const float* __restrict__ bf1,
           const float* __restrict__ Wf2, const float* __restrict__ bf2,
           const float* __restrict__ Wf3, const float* __restrict__ bf3,
           float* __restrict__ out) {
  __shared__ float s_in[32][68];    // 8.5 KB
  __shared__ float s_a1[32][260];   // 33.3 KB
  __shared__ float s_a2[32][260];   // 33.3 KB   -> 75 KB total, 2 blocks/CU
  int t = threadIdx.x;
  int base = blockIdx.x * 32;
  {
    int r = (t * 4) >> 6, c = (t * 4) & 63;
    *(float4*)&s_in[r][c] = *(const float4*)(X + (size_t)(base + r) * 64 + c);
    int t2 = t + 256;
    r = (t2 * 4) >> 6; c = (t2 * 4) & 63;
    *(float4*)&s_in[r][c] = *(const float4*)(X + (size_t)(base + r) * 64 + c);
  }
  __syncthreads();
  const int jt = t & 31;
  const int ng = t >> 5;
  const int r0 = ng * 4;
  float acc[4][8];

  // ---- Layer 1: 64 -> 256 ----
  #pragma unroll
  for (int ni = 0; ni < 4; ni++)
    #pragma unroll
    for (int jj = 0; jj < 8; jj++) acc[ni][jj] = 0.f;
  for (int k0 = 0; k0 < 64; k0 += 8) {
    float wr[8][8];
    #pragma unroll
    for (int kk = 0; kk < 8; kk++) {
      const float4* wp = (const float4*)(Wf1 + (size_t)(k0 + kk) * 256 + jt * 8);
      float4 w0 = wp[0], w1 = wp[1];
      wr[kk][0]=w0.x; wr[kk][1]=w0.y; wr[kk][2]=w0.z; wr[kk][3]=w0.w;
      wr[kk][4]=w1.x; wr[kk][5]=w1.y; wr[kk][6]=w1.z; wr[kk][7]=w1.w;
    }
    #pragma unroll
    for (int kk = 0; kk < 8; kk++) {
      float a0 = s_in[r0+0][k0+kk];
      float a1 = s_in[r0+1][k0+kk];
      float a2 = s_in[r0+2][k0+kk];
      float a3 = s_in[r0+3][k0+kk];
      #pragma unroll
      for (int jj = 0; jj < 8; jj++) {
        acc[0][jj] += a0 * wr[kk][jj];
        acc[1][jj] += a1 * wr[kk][jj];
        acc[2][jj] += a2 * wr[kk][jj];
        acc[3][jj] += a3 * wr[kk][jj];
      }
    }
  }
  #pragma unroll
  for (int ni = 0; ni < 4; ni++)
    #pragma unroll
    for (int jj = 0; jj < 8; jj++) {
      float v = acc[ni][jj] + bf1[jt * 8 + jj];
      s_a1[r0 + ni][jt * 8 + jj] = v > 0.f ? v : 0.f;
    }
  __syncthreads();

  // ---- Layer 2: 256 -> 256 ----
  #pragma unroll
  for (int ni = 0; ni < 4; ni++)
    #pragma unroll
    for (int jj = 0; jj < 8; jj++) acc[ni][jj] = 0.f;
  for (int k0 = 0; k0 < 256; k0 += 8) {
    float wr[8][8];
    #pragma unroll
    for (int kk = 0; kk < 8; kk++) {
      const float4* wp = (const float4*)(Wf2 + (size_t)(k0 + kk) * 256 + jt * 8);
      float4 w0 = wp[0], w1 = wp[1];
      wr[kk][0]=w0.x; wr[kk][1]=w0.y; wr[kk][2]=w0.z; wr[kk][3]=w0.w;
      wr[kk][4]=w1.x; wr[kk][5]=w1.y; wr[kk][6]=w1.z; wr[kk][7]=w1.w;
    }
    #pragma unroll
    for (int kk = 0; kk < 8; kk++) {
      float a0 = s_a1[r0+0][k0+kk];
      float a1 = s_a1[r0+1][k0+kk];
      float a2 = s_a1[r0+2][k0+kk];
      float a3 = s_a1[r0+3][k0+kk];
      #pragma unroll
      for (int jj = 0; jj < 8; jj++) {
        acc[0][jj] += a0 * wr[kk][jj];
        acc[1][jj] += a1 * wr[kk][jj];
        acc[2][jj] += a2 * wr[kk][jj];
        acc[3][jj] += a3 * wr[kk][jj];
      }
    }
  }
  #pragma unroll
  for (int ni = 0; ni < 4; ni++)
    #pragma unroll
    for (int jj = 0; jj < 8; jj++) {
      float v = acc[ni][jj] + bf2[jt * 8 + jj];
      s_a2[r0 + ni][jt * 8 + jj] = v > 0.f ? v : 0.f;
    }
  __syncthreads();

  // ---- Layer 3: 256 -> 128 ----
  float a3c[4][4];
  #pragma unroll
  for (int ni = 0; ni < 4; ni++)
    #pragma unroll
    for (int jj = 0; jj < 4; jj++) a3c[ni][jj] = 0.f;
  for (int k0 = 0; k0 < 256; k0 += 8) {
    float wr[8][4];
    #pragma unroll
    for (int kk = 0; kk < 8; kk++) {
      float4 w0 = *(const float4*)(Wf3 + (size_t)(k0 + kk) * 128 + jt * 4);
      wr[kk][0]=w0.x; wr[kk][1]=w0.y; wr[kk][2]=w0.z; wr[kk][3]=w0.w;
    }
    #pragma unroll
    for (int kk = 0; kk < 8; kk++) {
      float a0 = s_a2[r0+0][k0+kk];
      float a1 = s_a2[r0+1][k0+kk];
      float a2 = s_a2[r0+2][k0+kk];
      float a3 = s_a2[r0+3][k0+kk];
      #pragma unroll
      for (int jj = 0; jj < 4; jj++) {
        a3c[0][jj] += a0 * wr[kk][jj];
        a3c[1][jj] += a1 * wr[kk][jj];
        a3c[2][jj] += a2 * wr[kk][jj];
        a3c[3][jj] += a3 * wr[kk][jj];
      }
    }
  }
  #pragma unroll
  for (int ni = 0; ni < 4; ni++) {
    float4 v;
    v.x = a3c[ni][0] + bf3[jt * 4 + 0];
    v.y = a3c[ni][1] + bf3[jt * 4 + 1];
    v.z = a3c[ni][2] + bf3[jt * 4 + 2];
    v.w = a3c[ni][3] + bf3[jt * 4 + 3];
    v.x = v.x > 0.f ? v.x : 0.f;
    v.y = v.y > 0.f ? v.y : 0.f;
    v.z = v.z > 0.f ? v.z : 0.f;
    v.w = v.w > 0.f ? v.w : 0.f;
    *(float4*)(out + (size_t)(base + r0 + ni) * 128 + jt * 4) = v;
  }
}

// ---------------- launch ----------------

extern "C" void kernel_launch(void* const* d_in, const int* in_sizes, int n_in,
                              void* d_out, int out_size, void* d_ws, size_t ws_size,
                              hipStream_t stream) {
  const float* x   = (const float*)d_in[0];
  const int*   ei  = (const int*)d_in[1];
  const float* W1  = (const float*)d_in[2];
  const float* b1  = (const float*)d_in[3];
  const float* W2  = (const float*)d_in[4];
  const float* b2  = (const float*)d_in[5];
  const float* Wf1 = (const float*)d_in[6];
  const float* bf1 = (const float*)d_in[7];
  const float* Wf2 = (const float*)d_in[8];
  const float* bf2 = (const float*)d_in[9];
  const float* Wf3 = (const float*)d_in[10];
  const float* bf3 = (const float*)d_in[11];
  float* out = (float*)d_out;

  const int* src = ei;             // edge_index[0]
  const int* dst = ei + N_EDGES;   // edge_index[1]

  // workspace layout (int elements; everything 16B-aligned)
  int*   counts  = (int*)d_ws;
  int*   cursor  = counts + 100352;
  int*   offsets = cursor + 100352;      // N+1 used
  int*   bsums   = offsets + 100352;
  int*   bbase   = bsums + 256;
  int*   csr_src = bbase + 256;          // E ints
  float* dinv    = (float*)(csr_src + N_EDGES);
  float* bufA    = dinv + 100352;        // h (pre-aggregation), N*64
  float* bufB    = bufA + N_NODES * HID; // g (post-aggregation, ReLU'd), N*64

  hipMemsetAsync(counts, 0, 2 * 100352 * sizeof(int), stream);  // counts + cursor

  k_count     <<<(N_EDGES + 255) / 256, 256, 0, stream>>>(dst, counts);
  k_dinv      <<<(N_NODES + 255) / 256, 256, 0, stream>>>(counts, dinv);
  k_blocksums <<<SCAN_NB, 256, 0, stream>>>(counts, bsums);
  k_scan_bsums<<<1, 64, 0, stream>>>(bsums, bbase);
  k_offsets   <<<SCAN_NB, 256, 0, stream>>>(counts, bbase, offsets);
  k_fill      <<<(N_EDGES + 255) / 256, 256, 0, stream>>>(src, dst, offsets, cursor, csr_src);

  k_gemm64<IN_DIM><<<N_NODES / 32, 256, 0, stream>>>(x, W1, bufA);
  k_aggregate     <<<2048, 256, 0, stream>>>(bufA, offsets, csr_src, dinv, b1, bufB);
  k_gemm64<HID>   <<<N_NODES / 32, 256, 0, stream>>>(bufB, W2, bufA);
  k_aggregate     <<<2048, 256, 0, stream>>>(bufA, offsets, csr_src, dinv, b2, bufB);
  k_mlp           <<<N_NODES / 32, 256, 0, stream>>>(bufB, Wf1, bf1, Wf2, bf2, Wf3, bf3, out);
}

// Round 2
// 695.961 us; speedup vs baseline: 1.5914x; 1.5914x over previous
//
#include <hip/hip_runtime.h>

#define N_NODES 100000
#define N_EDGES 1600000
#define IN_DIM  128
#define HID     64
#define MLP_HID 256
#define OUT_DIM 128
#define SCAN_NB 98   // ceil(100000/1024)

typedef __attribute__((ext_vector_type(4))) float fx4;
typedef __attribute__((ext_vector_type(8))) short bf16x8;
typedef unsigned short u16;

// ---------------- bf16 hi/lo split helpers ----------------

__device__ __forceinline__ void bsplit(float x, unsigned& hb, unsigned& lb) {
  unsigned u = __float_as_uint(x);
  hb = (u + 0x7FFFu + ((u >> 16) & 1u)) >> 16;           // RNE to bf16
  float rl = x - __uint_as_float(hb << 16);              // exact residual
  unsigned ul = __float_as_uint(rl);
  lb = (ul + 0x7FFFu + ((ul >> 16) & 1u)) >> 16;
}

__device__ __forceinline__ void split8(const float* p, bf16x8& ah, bf16x8& al) {
  float4 f0 = *(const float4*)p;
  float4 f1 = *(const float4*)(p + 4);
  float f[8] = {f0.x, f0.y, f0.z, f0.w, f1.x, f1.y, f1.z, f1.w};
  #pragma unroll
  for (int j = 0; j < 8; j++) {
    unsigned hb, lb;
    bsplit(f[j], hb, lb);
    ah[j] = (short)hb;
    al[j] = (short)lb;
  }
}

// ---------------- graph build ----------------

__global__ void k_count(const int* __restrict__ dst, int* __restrict__ counts) {
  int e = blockIdx.x * 256 + threadIdx.x;
  if (e < N_EDGES) atomicAdd(&counts[dst[e]], 1);
}

__global__ void k_dinv(const int* __restrict__ counts, float* __restrict__ dinv) {
  int i = blockIdx.x * 256 + threadIdx.x;
  if (i < N_NODES) dinv[i] = rsqrtf((float)(counts[i] + 1));  // +1 self-loop
}

__global__ void k_blocksums(const int* __restrict__ counts, int* __restrict__ bsums) {
  __shared__ int sd[256];
  int b = blockIdx.x, t = threadIdx.x;
  int i0 = b * 1024 + t * 4;
  int s = 0;
  #pragma unroll
  for (int i = 0; i < 4; i++) { int idx = i0 + i; if (idx < N_NODES) s += counts[idx]; }
  sd[t] = s;
  __syncthreads();
  for (int off = 128; off > 0; off >>= 1) {
    if (t < off) sd[t] += sd[t + off];
    __syncthreads();
  }
  if (t == 0) bsums[b] = sd[0];
}

__global__ void k_scan_bsums(const int* __restrict__ bsums, int* __restrict__ bbase) {
  if (threadIdx.x == 0 && blockIdx.x == 0) {
    int run = 0;
    #pragma unroll 1
    for (int b = 0; b < SCAN_NB; b++) { bbase[b] = run; run += bsums[b]; }
  }
}

__global__ void k_offsets(const int* __restrict__ counts, const int* __restrict__ bbase,
                          int* __restrict__ offsets) {
  __shared__ int ts[256];
  int b = blockIdx.x, t = threadIdx.x;
  int i0 = b * 1024 + t * 4;
  int loc[4];
  #pragma unroll
  for (int i = 0; i < 4; i++) { int idx = i0 + i; loc[i] = (idx < N_NODES) ? counts[idx] : 0; }
  int my = loc[0] + loc[1] + loc[2] + loc[3];
  ts[t] = my;
  __syncthreads();
  int v = my;
  for (int off = 1; off < 256; off <<= 1) {
    int y = (t >= off) ? ts[t - off] : 0;
    __syncthreads();
    v += y;
    ts[t] = v;
    __syncthreads();
  }
  int run = v - my + bbase[b];
  #pragma unroll
  for (int i = 0; i < 4; i++) {
    int idx = i0 + i;
    if (idx < N_NODES) offsets[idx] = run;
    run += loc[i];
  }
  if (b == 0 && t == 0) offsets[N_NODES] = N_EDGES;
}

__global__ void k_fill(const int* __restrict__ src, const int* __restrict__ dst,
                       const int* __restrict__ offsets, int* __restrict__ cursor,
                       int* __restrict__ csr_src) {
  int e = blockIdx.x * 256 + threadIdx.x;
  if (e < N_EDGES) {
    int d = dst[e];
    int pos = offsets[d] + atomicAdd(&cursor[d], 1);
    csr_src[pos] = src[e];
  }
}

// ---------------- weight pre-pack into MFMA B-fragment order (bf16 hi/lo) ----------------
// Fragment for (ntile, ks): lane l holds B[k = ks*32 + (l>>4)*8 + j][col = ntile*16 + (l&15)],
// stored contiguously: idx = ((ntile*ksteps + ks)*64 + lane)*8 + j

__global__ void k_pack(const float* __restrict__ W, int K, int N,
                       u16* __restrict__ hi, u16* __restrict__ lo) {
  int tid = blockIdx.x * 256 + threadIdx.x;
  if (tid >= K * N) return;
  int k = tid / N, n = tid % N;
  unsigned hb, lb;
  bsplit(W[tid], hb, lb);
  int nt = n >> 4, col = n & 15;
  int ks = k >> 5, kr = k & 31;
  int lane = (kr >> 3) * 16 + col;
  int j = kr & 7;
  int ksteps = K >> 5;
  size_t idx = (((size_t)(nt * ksteps + ks)) * 64 + lane) * 8 + j;
  hi[idx] = (u16)hb;
  lo[idx] = (u16)lb;
}

// ---------------- conv linear: out[n] = (X[n] @ W) * dinv[n]  (pre-scaled, no bias) ----------

template<int K>
__global__ __launch_bounds__(256)
void k_gemm64(const float* __restrict__ X, const float* __restrict__ W,
              const float* __restrict__ dinv, float* __restrict__ out) {
  __shared__ float sx[32][K + 4];
  int t = threadIdx.x;
  int base = blockIdx.x * 32;
  const int tot4 = 32 * K / 4;
  for (int i = t; i < tot4; i += 256) {
    int f = i * 4;
    int r = f / K, c = f % K;
    *(float4*)&sx[r][c] = *(const float4*)(X + (size_t)(base + r) * K + c);
  }
  __syncthreads();
  const int jt = t & 7;
  const int n  = t >> 3;
  float acc[8];
  #pragma unroll
  for (int j = 0; j < 8; j++) acc[j] = 0.f;
  for (int k0 = 0; k0 < K; k0 += 8) {
    float wr[8][8];
    #pragma unroll
    for (int kk = 0; kk < 8; kk++) {
      const float4* wp = (const float4*)(W + (size_t)(k0 + kk) * 64 + jt * 8);
      float4 w0 = wp[0], w1 = wp[1];
      wr[kk][0] = w0.x; wr[kk][1] = w0.y; wr[kk][2] = w0.z; wr[kk][3] = w0.w;
      wr[kk][4] = w1.x; wr[kk][5] = w1.y; wr[kk][6] = w1.z; wr[kk][7] = w1.w;
    }
    #pragma unroll
    for (int kk = 0; kk < 8; kk++) {
      float xv = sx[n][k0 + kk];
      #pragma unroll
      for (int jj = 0; jj < 8; jj++) acc[jj] += xv * wr[kk][jj];
    }
  }
  float dv = dinv[base + n];
  float* op = out + (size_t)(base + n) * 64 + jt * 8;
  *(float4*)op       = make_float4(acc[0]*dv, acc[1]*dv, acc[2]*dv, acc[3]*dv);
  *(float4*)(op + 4) = make_float4(acc[4]*dv, acc[5]*dv, acc[6]*dv, acc[7]*dv);
}

// ---------------- aggregation: out[v] = ReLU(dinv[v]*(h'[v] + sum_s h'[s]) + b) --------------

__global__ __launch_bounds__(256)
void k_aggregate(const float* __restrict__ h, const int* __restrict__ offsets,
                 const int* __restrict__ csr_src, const float* __restrict__ dinv,
                 const float* __restrict__ bias, float* __restrict__ out) {
  int lane = threadIdx.x & 63;
  int wid = (blockIdx.x * 256 + threadIdx.x) >> 6;
  int nw = (gridDim.x * 256) >> 6;
  float bv = bias[lane];
  for (int v = wid; v < N_NODES; v += nw) {
    int e0 = offsets[v], e1 = offsets[v + 1];
    float acc = h[(size_t)v * 64 + lane];   // self-loop (pre-scaled)
    int e = e0;
    for (; e + 8 <= e1; e += 8) {
      int s0 = __builtin_amdgcn_readfirstlane(csr_src[e + 0]);
      int s1 = __builtin_amdgcn_readfirstlane(csr_src[e + 1]);
      int s2 = __builtin_amdgcn_readfirstlane(csr_src[e + 2]);
      int s3 = __builtin_amdgcn_readfirstlane(csr_src[e + 3]);
      int s4 = __builtin_amdgcn_readfirstlane(csr_src[e + 4]);
      int s5 = __builtin_amdgcn_readfirstlane(csr_src[e + 5]);
      int s6 = __builtin_amdgcn_readfirstlane(csr_src[e + 6]);
      int s7 = __builtin_amdgcn_readfirstlane(csr_src[e + 7]);
      float a0 = h[(size_t)s0 * 64 + lane];
      float a1 = h[(size_t)s1 * 64 + lane];
      float a2 = h[(size_t)s2 * 64 + lane];
      float a3 = h[(size_t)s3 * 64 + lane];
      float a4 = h[(size_t)s4 * 64 + lane];
      float a5 = h[(size_t)s5 * 64 + lane];
      float a6 = h[(size_t)s6 * 64 + lane];
      float a7 = h[(size_t)s7 * 64 + lane];
      acc += ((a0 + a1) + (a2 + a3)) + ((a4 + a5) + (a6 + a7));
    }
    for (; e < e1; e++) {
      int s = __builtin_amdgcn_readfirstlane(csr_src[e]);
      acc += h[(size_t)s * 64 + lane];
    }
    float r = acc * dinv[v] + bv;
    out[(size_t)v * 64 + lane] = r > 0.f ? r : 0.f;
  }
}

// ---------------- fused MLP via split-bf16 MFMA: 64 -> 256 -> 256 -> 128 ----------------
// 256 threads = 4 waves, 64 nodes/block (4 M-tiles of 16). Waves split the N dimension.
// Activations stored in LDS as bf16 hi/lo (split once at epilogue) -> K-loops are pure
// ds_read_b128 + global_load_dwordx4 + MFMA.

__global__ __launch_bounds__(256, 2)
void k_mlp(const float* __restrict__ X,
           const u16* __restrict__ w1h, const u16* __restrict__ w1l, const float* __restrict__ bb1,
           const u16* __restrict__ w2h, const u16* __restrict__ w2l, const float* __restrict__ bb2,
           const u16* __restrict__ w3h, const u16* __restrict__ w3l, const float* __restrict__ bb3,
           float* __restrict__ out) {
  __shared__ u16 s_h[64][264];   // 33.8 KB  (264 stride: 16B-aligned rows, 2-way banks max)
  __shared__ u16 s_l[64][264];   // 33.8 KB
  const int t = threadIdx.x;
  const int w = t >> 6, lane = t & 63;
  const int base = blockIdx.x * 64;
  const int lr = lane & 15;      // A row / B,D col within tile
  const int lg = lane >> 4;      // k-group
  const int kofs = lg * 8;
  const int dr = lg * 4;         // D row base

  fx4 acc[4][4];

  // ---- Layer 1: 64 -> 256 (ksteps=2), A from global ----
  #pragma unroll
  for (int m = 0; m < 4; m++)
    #pragma unroll
    for (int n = 0; n < 4; n++) acc[m][n] = (fx4){0.f, 0.f, 0.f, 0.f};
  #pragma unroll
  for (int ks = 0; ks < 2; ks++) {
    bf16x8 ah[4], al[4];
    #pragma unroll
    for (int m = 0; m < 4; m++) {
      int row = base + m * 16 + lr;
      if (row >= N_NODES) row = N_NODES - 1;
      split8(X + (size_t)row * 64 + ks * 32 + kofs, ah[m], al[m]);
    }
    #pragma unroll
    for (int n = 0; n < 4; n++) {
      size_t fi = ((size_t)((w * 4 + n) * 2 + ks) * 64 + lane) * 8;
      bf16x8 bh = *(const bf16x8*)(w1h + fi);
      bf16x8 bl = *(const bf16x8*)(w1l + fi);
      #pragma unroll
      for (int m = 0; m < 4; m++) {
        acc[m][n] = __builtin_amdgcn_mfma_f32_16x16x32_bf16(al[m], bh, acc[m][n], 0, 0, 0);
        acc[m][n] = __builtin_amdgcn_mfma_f32_16x16x32_bf16(ah[m], bl, acc[m][n], 0, 0, 0);
        acc[m][n] = __builtin_amdgcn_mfma_f32_16x16x32_bf16(ah[m], bh, acc[m][n], 0, 0, 0);
      }
    }
  }
  #pragma unroll
  for (int n = 0; n < 4; n++) {
    float bias = bb1[(w * 4 + n) * 16 + lr];
    #pragma unroll
    for (int m = 0; m < 4; m++)
      #pragma unroll
      for (int r = 0; r < 4; r++) {
        float v = acc[m][n][r] + bias;
        v = v > 0.f ? v : 0.f;
        unsigned hb, lb;
        bsplit(v, hb, lb);
        s_h[m * 16 + dr + r][(w * 4 + n) * 16 + lr] = (u16)hb;
        s_l[m * 16 + dr + r][(w * 4 + n) * 16 + lr] = (u16)lb;
      }
  }
  __syncthreads();

  // ---- Layer 2: 256 -> 256 (ksteps=8), A from LDS (pre-split) ----
  #pragma unroll
  for (int m = 0; m < 4; m++)
    #pragma unroll
    for (int n = 0; n < 4; n++) acc[m][n] = (fx4){0.f, 0.f, 0.f, 0.f};
  for (int ks = 0; ks < 8; ks++) {
    bf16x8 ah[4], al[4];
    #pragma unroll
    for (int m = 0; m < 4; m++) {
      ah[m] = *(const bf16x8*)&s_h[m * 16 + lr][ks * 32 + kofs];
      al[m] = *(const bf16x8*)&s_l[m * 16 + lr][ks * 32 + kofs];
    }
    #pragma unroll
    for (int n = 0; n < 4; n++) {
      size_t fi = ((size_t)((w * 4 + n) * 8 + ks) * 64 + lane) * 8;
      bf16x8 bh = *(const bf16x8*)(w2h + fi);
      bf16x8 bl = *(const bf16x8*)(w2l + fi);
      #pragma unroll
      for (int m = 0; m < 4; m++) {
        acc[m][n] = __builtin_amdgcn_mfma_f32_16x16x32_bf16(al[m], bh, acc[m][n], 0, 0, 0);
        acc[m][n] = __builtin_amdgcn_mfma_f32_16x16x32_bf16(ah[m], bl, acc[m][n], 0, 0, 0);
        acc[m][n] = __builtin_amdgcn_mfma_f32_16x16x32_bf16(ah[m], bh, acc[m][n], 0, 0, 0);
      }
    }
  }
  __syncthreads();   // all LDS reads done before overwrite
  #pragma unroll
  for (int n = 0; n < 4; n++) {
    float bias = bb2[(w * 4 + n) * 16 + lr];
    #pragma unroll
    for (int m = 0; m < 4; m++)
      #pragma unroll
      for (int r = 0; r < 4; r++) {
        float v = acc[m][n][r] + bias;
        v = v > 0.f ? v : 0.f;
        unsigned hb, lb;
        bsplit(v, hb, lb);
        s_h[m * 16 + dr + r][(w * 4 + n) * 16 + lr] = (u16)hb;
        s_l[m * 16 + dr + r][(w * 4 + n) * 16 + lr] = (u16)lb;
      }
  }
  __syncthreads();

  // ---- Layer 3: 256 -> 128 (ksteps=8), 2 n-tiles per wave ----
  fx4 a3[4][2];
  #pragma unroll
  for (int m = 0; m < 4; m++)
    #pragma unroll
    for (int i = 0; i < 2; i++) a3[m][i] = (fx4){0.f, 0.f, 0.f, 0.f};
  for (int ks = 0; ks < 8; ks++) {
    bf16x8 ah[4], al[4];
    #pragma unroll
    for (int m = 0; m < 4; m++) {
      ah[m] = *(const bf16x8*)&s_h[m * 16 + lr][ks * 32 + kofs];
      al[m] = *(const bf16x8*)&s_l[m * 16 + lr][ks * 32 + kofs];
    }
    #pragma unroll
    for (int i = 0; i < 2; i++) {
      size_t fi = ((size_t)((w * 2 + i) * 8 + ks) * 64 + lane) * 8;
      bf16x8 bh = *(const bf16x8*)(w3h + fi);
      bf16x8 bl = *(const bf16x8*)(w3l + fi);
      #pragma unroll
      for (int m = 0; m < 4; m++) {
        a3[m][i] = __builtin_amdgcn_mfma_f32_16x16x32_bf16(al[m], bh, a3[m][i], 0, 0, 0);
        a3[m][i] = __builtin_amdgcn_mfma_f32_16x16x32_bf16(ah[m], bl, a3[m][i], 0, 0, 0);
        a3[m][i] = __builtin_amdgcn_mfma_f32_16x16x32_bf16(ah[m], bh, a3[m][i], 0, 0, 0);
      }
    }
  }
  #pragma unroll
  for (int i = 0; i < 2; i++) {
    int col = (w * 2 + i) * 16 + lr;
    float bias = bb3[col];
    #pragma unroll
    for (int m = 0; m < 4; m++)
      #pragma unroll
      for (int r = 0; r < 4; r++) {
        int row = base + m * 16 + dr + r;
        if (row < N_NODES) {
          float v = a3[m][i][r] + bias;
          out[(size_t)row * 128 + col] = v > 0.f ? v : 0.f;
        }
      }
  }
}

// ---------------- launch ----------------

extern "C" void kernel_launch(void* const* d_in, const int* in_sizes, int n_in,
                              void* d_out, int out_size, void* d_ws, size_t ws_size,
                              hipStream_t stream) {
  const float* x   = (const float*)d_in[0];
  const int*   ei  = (const int*)d_in[1];
  const float* W1  = (const float*)d_in[2];
  const float* b1  = (const float*)d_in[3];
  const float* W2  = (const float*)d_in[4];
  const float* b2  = (const float*)d_in[5];
  const float* Wf1 = (const float*)d_in[6];
  const float* bf1 = (const float*)d_in[7];
  const float* Wf2 = (const float*)d_in[8];
  const float* bf2 = (const float*)d_in[9];
  const float* Wf3 = (const float*)d_in[10];
  const float* bf3 = (const float*)d_in[11];
  float* out = (float*)d_out;

  const int* src = ei;             // edge_index[0]
  const int* dst = ei + N_EDGES;   // edge_index[1]

  // workspace layout (16B-aligned chunks)
  int*   counts  = (int*)d_ws;
  int*   cursor  = counts + 100352;
  int*   offsets = cursor + 100352;
  int*   bsums   = offsets + 100352;
  int*   bbase   = bsums + 256;
  int*   csr_src = bbase + 256;
  float* dinv    = (float*)(csr_src + N_EDGES);
  float* bufA    = dinv + 100352;
  float* bufB    = bufA + N_NODES * HID;
  u16*   p1h     = (u16*)(bufB + N_NODES * HID);
  u16*   p1l     = p1h + HID * MLP_HID;        // 16384
  u16*   p2h     = p1l + HID * MLP_HID;
  u16*   p2l     = p2h + MLP_HID * MLP_HID;    // 65536
  u16*   p3h     = p2l + MLP_HID * MLP_HID;
  u16*   p3l     = p3h + MLP_HID * OUT_DIM;    // 32768

  hipMemsetAsync(counts, 0, 2 * 100352 * sizeof(int), stream);  // counts + cursor

  k_count     <<<(N_EDGES + 255) / 256, 256, 0, stream>>>(dst, counts);
  k_dinv      <<<(N_NODES + 255) / 256, 256, 0, stream>>>(counts, dinv);
  k_blocksums <<<SCAN_NB, 256, 0, stream>>>(counts, bsums);
  k_scan_bsums<<<1, 64, 0, stream>>>(bsums, bbase);
  k_offsets   <<<SCAN_NB, 256, 0, stream>>>(counts, bbase, offsets);
  k_fill      <<<(N_EDGES + 255) / 256, 256, 0, stream>>>(src, dst, offsets, cursor, csr_src);

  k_pack<<<(HID * MLP_HID + 255) / 256, 256, 0, stream>>>(Wf1, HID, MLP_HID, p1h, p1l);
  k_pack<<<(MLP_HID * MLP_HID + 255) / 256, 256, 0, stream>>>(Wf2, MLP_HID, MLP_HID, p2h, p2l);
  k_pack<<<(MLP_HID * OUT_DIM + 255) / 256, 256, 0, stream>>>(Wf3, MLP_HID, OUT_DIM, p3h, p3l);

  k_gemm64<IN_DIM><<<N_NODES / 32, 256, 0, stream>>>(x, W1, dinv, bufA);
  k_aggregate     <<<4096, 256, 0, stream>>>(bufA, offsets, csr_src, dinv, b1, bufB);
  k_gemm64<HID>   <<<N_NODES / 32, 256, 0, stream>>>(bufB, W2, dinv, bufA);
  k_aggregate     <<<4096, 256, 0, stream>>>(bufA, offsets, csr_src, dinv, b2, bufB);

  k_mlp<<<(N_NODES + 63) / 64, 256, 0, stream>>>(bufB, p1h, p1l, bf1, p2h, p2l, bf2,
                                                 p3h, p3l, bf3, out);
}

// Round 3
// 599.876 us; speedup vs baseline: 1.8463x; 1.1602x over previous
//
#include <hip/hip_runtime.h>

#define N_NODES 100000
#define N_EDGES 1600000
#define IN_DIM  128
#define HID     64
#define MLP_HID 256
#define OUT_DIM 128
#define SCAN_NB 98   // ceil(100000/1024)

typedef __attribute__((ext_vector_type(4))) float fx4;
typedef __attribute__((ext_vector_type(8))) short bf16x8;
typedef __attribute__((ext_vector_type(4))) unsigned short u16x4;
typedef unsigned short u16;

// ---------------- bf16 hi/lo split helpers ----------------

__device__ __forceinline__ void bsplit(float x, unsigned& hb, unsigned& lb) {
  unsigned u = __float_as_uint(x);
  hb = (u + 0x7FFFu + ((u >> 16) & 1u)) >> 16;           // RNE to bf16
  float rl = x - __uint_as_float(hb << 16);              // exact residual
  unsigned ul = __float_as_uint(rl);
  lb = (ul + 0x7FFFu + ((ul >> 16) & 1u)) >> 16;
}

__device__ __forceinline__ void split8(const float* p, bf16x8& ah, bf16x8& al) {
  float4 f0 = *(const float4*)p;
  float4 f1 = *(const float4*)(p + 4);
  float f[8] = {f0.x, f0.y, f0.z, f0.w, f1.x, f1.y, f1.z, f1.w};
  #pragma unroll
  for (int j = 0; j < 8; j++) {
    unsigned hb, lb;
    bsplit(f[j], hb, lb);
    ah[j] = (short)hb;
    al[j] = (short)lb;
  }
}

// ---------------- graph build ----------------

__global__ void k_count(const int* __restrict__ dst, int* __restrict__ counts) {
  int e = blockIdx.x * 256 + threadIdx.x;
  if (e < N_EDGES) atomicAdd(&counts[dst[e]], 1);
}

__global__ void k_dinv(const int* __restrict__ counts, float* __restrict__ dinv) {
  int i = blockIdx.x * 256 + threadIdx.x;
  if (i < N_NODES) dinv[i] = rsqrtf((float)(counts[i] + 1));  // +1 self-loop
}

__global__ void k_blocksums(const int* __restrict__ counts, int* __restrict__ bsums) {
  __shared__ int sd[256];
  int b = blockIdx.x, t = threadIdx.x;
  int i0 = b * 1024 + t * 4;
  int s = 0;
  #pragma unroll
  for (int i = 0; i < 4; i++) { int idx = i0 + i; if (idx < N_NODES) s += counts[idx]; }
  sd[t] = s;
  __syncthreads();
  for (int off = 128; off > 0; off >>= 1) {
    if (t < off) sd[t] += sd[t + off];
    __syncthreads();
  }
  if (t == 0) bsums[b] = sd[0];
}

__global__ void k_scan_bsums(const int* __restrict__ bsums, int* __restrict__ bbase) {
  if (threadIdx.x == 0 && blockIdx.x == 0) {
    int run = 0;
    #pragma unroll 1
    for (int b = 0; b < SCAN_NB; b++) { bbase[b] = run; run += bsums[b]; }
  }
}

__global__ void k_offsets(const int* __restrict__ counts, const int* __restrict__ bbase,
                          int* __restrict__ offsets, int* __restrict__ cursor) {
  __shared__ int ts[256];
  int b = blockIdx.x, t = threadIdx.x;
  int i0 = b * 1024 + t * 4;
  int loc[4];
  #pragma unroll
  for (int i = 0; i < 4; i++) { int idx = i0 + i; loc[i] = (idx < N_NODES) ? counts[idx] : 0; }
  int my = loc[0] + loc[1] + loc[2] + loc[3];
  ts[t] = my;
  __syncthreads();
  int v = my;
  for (int off = 1; off < 256; off <<= 1) {
    int y = (t >= off) ? ts[t - off] : 0;
    __syncthreads();
    v += y;
    ts[t] = v;
    __syncthreads();
  }
  int run = v - my + bbase[b];
  #pragma unroll
  for (int i = 0; i < 4; i++) {
    int idx = i0 + i;
    if (idx < N_NODES) { offsets[idx] = run; cursor[idx] = run; }
    run += loc[i];
  }
  if (b == 0 && t == 0) offsets[N_NODES] = N_EDGES;
}

// cursor pre-initialized to offsets: one atomic gives the slot, no offsets gather
__global__ void k_fill(const int* __restrict__ src, const int* __restrict__ dst,
                       int* __restrict__ cursor, int* __restrict__ csr_src) {
  int e = blockIdx.x * 256 + threadIdx.x;
  if (e < N_EDGES) {
    int pos = atomicAdd(&cursor[dst[e]], 1);
    csr_src[pos] = src[e];
  }
}

// ---------------- weight pre-pack into MFMA B-fragment order (bf16 hi/lo) ----------------
// Fragment for (ntile, ks): lane l holds B[k = ks*32 + (l>>4)*8 + j][col = ntile*16 + (l&15)],
// stored contiguously: idx = ((ntile*ksteps + ks)*64 + lane)*8 + j

__global__ void k_pack(const float* __restrict__ W, int K, int N,
                       u16* __restrict__ hi, u16* __restrict__ lo) {
  int tid = blockIdx.x * 256 + threadIdx.x;
  if (tid >= K * N) return;
  int k = tid / N, n = tid % N;
  unsigned hb, lb;
  bsplit(W[tid], hb, lb);
  int nt = n >> 4, col = n & 15;
  int ks = k >> 5, kr = k & 31;
  int lane = (kr >> 3) * 16 + col;
  int j = kr & 7;
  int ksteps = K >> 5;
  size_t idx = (((size_t)(nt * ksteps + ks)) * 64 + lane) * 8 + j;
  hi[idx] = (u16)hb;
  lo[idx] = (u16)lb;
}

// ---------------- conv linear via split-bf16 MFMA: out[n] = (X[n] @ W) * dinv[n] -------------
// 256 threads = 4 waves, 64 nodes/block. X-tile staged to LDS pre-split (hi/lo bf16).
// Wave w owns n-tile w (cols w*16..w*16+15). 3 MFMAs per hi/lo product.

template<int K>
__global__ __launch_bounds__(256, 2)
void k_conv(const float* __restrict__ X, const u16* __restrict__ wh, const u16* __restrict__ wl,
            const float* __restrict__ dinv, float* __restrict__ out) {
  constexpr int KS = K / 32;
  constexpr int STRIDE = K + 8;
  __shared__ u16 s_h[64][STRIDE];
  __shared__ u16 s_l[64][STRIDE];
  const int t = threadIdx.x;
  const int base = blockIdx.x * 64;

  // stage + split
  const int tot4 = 64 * K / 4;
  for (int i = t; i < tot4; i += 256) {
    int f = i * 4;
    int r = f / K, c = f % K;
    int row = base + r;
    if (row >= N_NODES) row = N_NODES - 1;
    float4 v = *(const float4*)(X + (size_t)row * K + c);
    u16x4 h4, l4;
    unsigned hb, lb;
    bsplit(v.x, hb, lb); h4[0] = (u16)hb; l4[0] = (u16)lb;
    bsplit(v.y, hb, lb); h4[1] = (u16)hb; l4[1] = (u16)lb;
    bsplit(v.z, hb, lb); h4[2] = (u16)hb; l4[2] = (u16)lb;
    bsplit(v.w, hb, lb); h4[3] = (u16)hb; l4[3] = (u16)lb;
    *(u16x4*)&s_h[r][c] = h4;
    *(u16x4*)&s_l[r][c] = l4;
  }
  __syncthreads();

  const int w = t >> 6, lane = t & 63;
  const int lr = lane & 15;
  const int lg = lane >> 4;
  const int kofs = lg * 8;
  const int dr = lg * 4;

  fx4 acc[4];
  #pragma unroll
  for (int m = 0; m < 4; m++) acc[m] = (fx4){0.f, 0.f, 0.f, 0.f};

  #pragma unroll
  for (int ks = 0; ks < KS; ks++) {
    size_t fi = ((size_t)(w * KS + ks) * 64 + lane) * 8;
    bf16x8 bh = *(const bf16x8*)(wh + fi);
    bf16x8 bl = *(const bf16x8*)(wl + fi);
    #pragma unroll
    for (int m = 0; m < 4; m++) {
      bf16x8 ah = *(const bf16x8*)&s_h[m * 16 + lr][ks * 32 + kofs];
      bf16x8 al = *(const bf16x8*)&s_l[m * 16 + lr][ks * 32 + kofs];
      acc[m] = __builtin_amdgcn_mfma_f32_16x16x32_bf16(al, bh, acc[m], 0, 0, 0);
      acc[m] = __builtin_amdgcn_mfma_f32_16x16x32_bf16(ah, bl, acc[m], 0, 0, 0);
      acc[m] = __builtin_amdgcn_mfma_f32_16x16x32_bf16(ah, bh, acc[m], 0, 0, 0);
    }
  }

  #pragma unroll
  for (int m = 0; m < 4; m++)
    #pragma unroll
    for (int r = 0; r < 4; r++) {
      int row = base + m * 16 + dr + r;
      if (row < N_NODES)
        out[(size_t)row * 64 + w * 16 + lr] = acc[m][r] * dinv[row];
    }
}

// ---------------- aggregation: out[v] = ReLU(dinv[v]*(h'[v] + sum_s h'[s]) + b) --------------

__global__ __launch_bounds__(256)
void k_aggregate(const float* __restrict__ h, const int* __restrict__ offsets,
                 const int* __restrict__ csr_src, const float* __restrict__ dinv,
                 const float* __restrict__ bias, float* __restrict__ out) {
  int lane = threadIdx.x & 63;
  int wid = (blockIdx.x * 256 + threadIdx.x) >> 6;
  int nw = (gridDim.x * 256) >> 6;
  float bv = bias[lane];
  for (int v = wid; v < N_NODES; v += nw) {
    int e0 = offsets[v], e1 = offsets[v + 1];
    float acc = h[(size_t)v * 64 + lane];   // self-loop (pre-scaled)
    int e = e0;
    for (; e + 8 <= e1; e += 8) {
      int s0 = __builtin_amdgcn_readfirstlane(csr_src[e + 0]);
      int s1 = __builtin_amdgcn_readfirstlane(csr_src[e + 1]);
      int s2 = __builtin_amdgcn_readfirstlane(csr_src[e + 2]);
      int s3 = __builtin_amdgcn_readfirstlane(csr_src[e + 3]);
      int s4 = __builtin_amdgcn_readfirstlane(csr_src[e + 4]);
      int s5 = __builtin_amdgcn_readfirstlane(csr_src[e + 5]);
      int s6 = __builtin_amdgcn_readfirstlane(csr_src[e + 6]);
      int s7 = __builtin_amdgcn_readfirstlane(csr_src[e + 7]);
      float a0 = h[(size_t)s0 * 64 + lane];
      float a1 = h[(size_t)s1 * 64 + lane];
      float a2 = h[(size_t)s2 * 64 + lane];
      float a3 = h[(size_t)s3 * 64 + lane];
      float a4 = h[(size_t)s4 * 64 + lane];
      float a5 = h[(size_t)s5 * 64 + lane];
      float a6 = h[(size_t)s6 * 64 + lane];
      float a7 = h[(size_t)s7 * 64 + lane];
      acc += ((a0 + a1) + (a2 + a3)) + ((a4 + a5) + (a6 + a7));
    }
    for (; e < e1; e++) {
      int s = __builtin_amdgcn_readfirstlane(csr_src[e]);
      acc += h[(size_t)s * 64 + lane];
    }
    float r = acc * dinv[v] + bv;
    out[(size_t)v * 64 + lane] = r > 0.f ? r : 0.f;
  }
}

// ---------------- fused MLP via split-bf16 MFMA: 64 -> 256 -> 256 -> 128 ----------------

__global__ __launch_bounds__(256, 2)
void k_mlp(const float* __restrict__ X,
           const u16* __restrict__ w1h, const u16* __restrict__ w1l, const float* __restrict__ bb1,
           const u16* __restrict__ w2h, const u16* __restrict__ w2l, const float* __restrict__ bb2,
           const u16* __restrict__ w3h, const u16* __restrict__ w3l, const float* __restrict__ bb3,
           float* __restrict__ out) {
  __shared__ u16 s_h[64][264];
  __shared__ u16 s_l[64][264];
  const int t = threadIdx.x;
  const int w = t >> 6, lane = t & 63;
  const int base = blockIdx.x * 64;
  const int lr = lane & 15;
  const int lg = lane >> 4;
  const int kofs = lg * 8;
  const int dr = lg * 4;

  fx4 acc[4][4];

  // ---- Layer 1: 64 -> 256 (ksteps=2), A from global ----
  #pragma unroll
  for (int m = 0; m < 4; m++)
    #pragma unroll
    for (int n = 0; n < 4; n++) acc[m][n] = (fx4){0.f, 0.f, 0.f, 0.f};
  #pragma unroll
  for (int ks = 0; ks < 2; ks++) {
    bf16x8 ah[4], al[4];
    #pragma unroll
    for (int m = 0; m < 4; m++) {
      int row = base + m * 16 + lr;
      if (row >= N_NODES) row = N_NODES - 1;
      split8(X + (size_t)row * 64 + ks * 32 + kofs, ah[m], al[m]);
    }
    #pragma unroll
    for (int n = 0; n < 4; n++) {
      size_t fi = ((size_t)((w * 4 + n) * 2 + ks) * 64 + lane) * 8;
      bf16x8 bh = *(const bf16x8*)(w1h + fi);
      bf16x8 bl = *(const bf16x8*)(w1l + fi);
      #pragma unroll
      for (int m = 0; m < 4; m++) {
        acc[m][n] = __builtin_amdgcn_mfma_f32_16x16x32_bf16(al[m], bh, acc[m][n], 0, 0, 0);
        acc[m][n] = __builtin_amdgcn_mfma_f32_16x16x32_bf16(ah[m], bl, acc[m][n], 0, 0, 0);
        acc[m][n] = __builtin_amdgcn_mfma_f32_16x16x32_bf16(ah[m], bh, acc[m][n], 0, 0, 0);
      }
    }
  }
  #pragma unroll
  for (int n = 0; n < 4; n++) {
    float bias = bb1[(w * 4 + n) * 16 + lr];
    #pragma unroll
    for (int m = 0; m < 4; m++)
      #pragma unroll
      for (int r = 0; r < 4; r++) {
        float v = acc[m][n][r] + bias;
        v = v > 0.f ? v : 0.f;
        unsigned hb, lb;
        bsplit(v, hb, lb);
        s_h[m * 16 + dr + r][(w * 4 + n) * 16 + lr] = (u16)hb;
        s_l[m * 16 + dr + r][(w * 4 + n) * 16 + lr] = (u16)lb;
      }
  }
  __syncthreads();

  // ---- Layer 2: 256 -> 256 (ksteps=8) ----
  #pragma unroll
  for (int m = 0; m < 4; m++)
    #pragma unroll
    for (int n = 0; n < 4; n++) acc[m][n] = (fx4){0.f, 0.f, 0.f, 0.f};
  for (int ks = 0; ks < 8; ks++) {
    bf16x8 ah[4], al[4];
    #pragma unroll
    for (int m = 0; m < 4; m++) {
      ah[m] = *(const bf16x8*)&s_h[m * 16 + lr][ks * 32 + kofs];
      al[m] = *(const bf16x8*)&s_l[m * 16 + lr][ks * 32 + kofs];
    }
    #pragma unroll
    for (int n = 0; n < 4; n++) {
      size_t fi = ((size_t)((w * 4 + n) * 8 + ks) * 64 + lane) * 8;
      bf16x8 bh = *(const bf16x8*)(w2h + fi);
      bf16x8 bl = *(const bf16x8*)(w2l + fi);
      #pragma unroll
      for (int m = 0; m < 4; m++) {
        acc[m][n] = __builtin_amdgcn_mfma_f32_16x16x32_bf16(al[m], bh, acc[m][n], 0, 0, 0);
        acc[m][n] = __builtin_amdgcn_mfma_f32_16x16x32_bf16(ah[m], bl, acc[m][n], 0, 0, 0);
        acc[m][n] = __builtin_amdgcn_mfma_f32_16x16x32_bf16(ah[m], bh, acc[m][n], 0, 0, 0);
      }
    }
  }
  __syncthreads();
  #pragma unroll
  for (int n = 0; n < 4; n++) {
    float bias = bb2[(w * 4 + n) * 16 + lr];
    #pragma unroll
    for (int m = 0; m < 4; m++)
      #pragma unroll
      for (int r = 0; r < 4; r++) {
        float v = acc[m][n][r] + bias;
        v = v > 0.f ? v : 0.f;
        unsigned hb, lb;
        bsplit(v, hb, lb);
        s_h[m * 16 + dr + r][(w * 4 + n) * 16 + lr] = (u16)hb;
        s_l[m * 16 + dr + r][(w * 4 + n) * 16 + lr] = (u16)lb;
      }
  }
  __syncthreads();

  // ---- Layer 3: 256 -> 128 (ksteps=8), 2 n-tiles per wave ----
  fx4 a3[4][2];
  #pragma unroll
  for (int m = 0; m < 4; m++)
    #pragma unroll
    for (int i = 0; i < 2; i++) a3[m][i] = (fx4){0.f, 0.f, 0.f, 0.f};
  for (int ks = 0; ks < 8; ks++) {
    bf16x8 ah[4], al[4];
    #pragma unroll
    for (int m = 0; m < 4; m++) {
      ah[m] = *(const bf16x8*)&s_h[m * 16 + lr][ks * 32 + kofs];
      al[m] = *(const bf16x8*)&s_l[m * 16 + lr][ks * 32 + kofs];
    }
    #pragma unroll
    for (int i = 0; i < 2; i++) {
      size_t fi = ((size_t)((w * 2 + i) * 8 + ks) * 64 + lane) * 8;
      bf16x8 bh = *(const bf16x8*)(w3h + fi);
      bf16x8 bl = *(const bf16x8*)(w3l + fi);
      #pragma unroll
      for (int m = 0; m < 4; m++) {
        a3[m][i] = __builtin_amdgcn_mfma_f32_16x16x32_bf16(al[m], bh, a3[m][i], 0, 0, 0);
        a3[m][i] = __builtin_amdgcn_mfma_f32_16x16x32_bf16(ah[m], bl, a3[m][i], 0, 0, 0);
        a3[m][i] = __builtin_amdgcn_mfma_f32_16x16x32_bf16(ah[m], bh, a3[m][i], 0, 0, 0);
      }
    }
  }
  #pragma unroll
  for (int i = 0; i < 2; i++) {
    int col = (w * 2 + i) * 16 + lr;
    float bias = bb3[col];
    #pragma unroll
    for (int m = 0; m < 4; m++)
      #pragma unroll
      for (int r = 0; r < 4; r++) {
        int row = base + m * 16 + dr + r;
        if (row < N_NODES) {
          float v = a3[m][i][r] + bias;
          out[(size_t)row * 128 + col] = v > 0.f ? v : 0.f;
        }
      }
  }
}

// ---------------- launch ----------------

extern "C" void kernel_launch(void* const* d_in, const int* in_sizes, int n_in,
                              void* d_out, int out_size, void* d_ws, size_t ws_size,
                              hipStream_t stream) {
  const float* x   = (const float*)d_in[0];
  const int*   ei  = (const int*)d_in[1];
  const float* W1  = (const float*)d_in[2];
  const float* b1  = (const float*)d_in[3];
  const float* W2  = (const float*)d_in[4];
  const float* b2  = (const float*)d_in[5];
  const float* Wf1 = (const float*)d_in[6];
  const float* bf1 = (const float*)d_in[7];
  const float* Wf2 = (const float*)d_in[8];
  const float* bf2 = (const float*)d_in[9];
  const float* Wf3 = (const float*)d_in[10];
  const float* bf3 = (const float*)d_in[11];
  float* out = (float*)d_out;

  const int* src = ei;             // edge_index[0]
  const int* dst = ei + N_EDGES;   // edge_index[1]

  // workspace layout (16B-aligned chunks)
  int*   counts  = (int*)d_ws;
  int*   cursor  = counts + 100352;
  int*   offsets = cursor + 100352;
  int*   bsums   = offsets + 100352;
  int*   bbase   = bsums + 256;
  int*   csr_src = bbase + 256;
  float* dinv    = (float*)(csr_src + N_EDGES);
  float* bufA    = dinv + 100352;
  float* bufB    = bufA + N_NODES * HID;
  u16*   p1h     = (u16*)(bufB + N_NODES * HID);
  u16*   p1l     = p1h + HID * MLP_HID;
  u16*   p2h     = p1l + HID * MLP_HID;
  u16*   p2l     = p2h + MLP_HID * MLP_HID;
  u16*   p3h     = p2l + MLP_HID * MLP_HID;
  u16*   p3l     = p3h + MLP_HID * OUT_DIM;
  u16*   pw1h    = p3l + MLP_HID * OUT_DIM;
  u16*   pw1l    = pw1h + IN_DIM * HID;
  u16*   pw2h    = pw1l + IN_DIM * HID;
  u16*   pw2l    = pw2h + HID * HID;

  hipMemsetAsync(counts, 0, 100352 * sizeof(int), stream);  // counts only

  k_count     <<<(N_EDGES + 255) / 256, 256, 0, stream>>>(dst, counts);
  k_dinv      <<<(N_NODES + 255) / 256, 256, 0, stream>>>(counts, dinv);
  k_blocksums <<<SCAN_NB, 256, 0, stream>>>(counts, bsums);
  k_scan_bsums<<<1, 64, 0, stream>>>(bsums, bbase);
  k_offsets   <<<SCAN_NB, 256, 0, stream>>>(counts, bbase, offsets, cursor);
  k_fill      <<<(N_EDGES + 255) / 256, 256, 0, stream>>>(src, dst, cursor, csr_src);

  k_pack<<<(HID * MLP_HID + 255) / 256, 256, 0, stream>>>(Wf1, HID, MLP_HID, p1h, p1l);
  k_pack<<<(MLP_HID * MLP_HID + 255) / 256, 256, 0, stream>>>(Wf2, MLP_HID, MLP_HID, p2h, p2l);
  k_pack<<<(MLP_HID * OUT_DIM + 255) / 256, 256, 0, stream>>>(Wf3, MLP_HID, OUT_DIM, p3h, p3l);
  k_pack<<<(IN_DIM * HID + 255) / 256, 256, 0, stream>>>(W1, IN_DIM, HID, pw1h, pw1l);
  k_pack<<<(HID * HID + 255) / 256, 256, 0, stream>>>(W2, HID, HID, pw2h, pw2l);

  k_conv<IN_DIM><<<(N_NODES + 63) / 64, 256, 0, stream>>>(x, pw1h, pw1l, dinv, bufA);
  k_aggregate    <<<4096, 256, 0, stream>>>(bufA, offsets, csr_src, dinv, b1, bufB);
  k_conv<HID>    <<<(N_NODES + 63) / 64, 256, 0, stream>>>(bufB, pw2h, pw2l, dinv, bufA);
  k_aggregate    <<<4096, 256, 0, stream>>>(bufA, offsets, csr_src, dinv, b2, bufB);

  k_mlp<<<(N_NODES + 63) / 64, 256, 0, stream>>>(bufB, p1h, p1l, bf1, p2h, p2l, bf2,
                                                 p3h, p3l, bf3, out);
}

// Round 4
// 509.139 us; speedup vs baseline: 2.1754x; 1.1782x over previous
//
#include <hip/hip_runtime.h>

#define N_NODES 100000
#define N_EDGES 1600000
#define IN_DIM  128
#define HID     64
#define MLP_HID 256
#define OUT_DIM 128
#define SCAN_NB 98   // ceil(100000/1024)

#define CB_SHIFT 9
#define CB_SIZE  512
#define NB_C     196  // ceil(100000/512)

typedef __attribute__((ext_vector_type(4))) float fx4;
typedef __attribute__((ext_vector_type(8))) short bf16x8;
typedef __attribute__((ext_vector_type(4))) unsigned short u16x4;
typedef unsigned short u16;
typedef unsigned long long u64;

// ---------------- bf16 hi/lo split helpers ----------------

__device__ __forceinline__ void bsplit(float x, unsigned& hb, unsigned& lb) {
  unsigned u = __float_as_uint(x);
  hb = (u + 0x7FFFu + ((u >> 16) & 1u)) >> 16;           // RNE to bf16
  float rl = x - __uint_as_float(hb << 16);              // exact residual
  unsigned ul = __float_as_uint(rl);
  lb = (ul + 0x7FFFu + ((ul >> 16) & 1u)) >> 16;
}

__device__ __forceinline__ void split8(const float* p, bf16x8& ah, bf16x8& al) {
  float4 f0 = *(const float4*)p;
  float4 f1 = *(const float4*)(p + 4);
  float f[8] = {f0.x, f0.y, f0.z, f0.w, f1.x, f1.y, f1.z, f1.w};
  #pragma unroll
  for (int j = 0; j < 8; j++) {
    unsigned hb, lb;
    bsplit(f[j], hb, lb);
    ah[j] = (short)hb;
    al[j] = (short)lb;
  }
}

// ---------------- graph build: bucketed counting sort ----------------

// P0: coarse histogram of dst>>9
__global__ __launch_bounds__(256)
void k_coarse_hist(const int* __restrict__ dst, int* __restrict__ chist) {
  __shared__ int h[NB_C];
  for (int i = threadIdx.x; i < NB_C; i += 256) h[i] = 0;
  __syncthreads();
  int base = blockIdx.x * 4096;
  #pragma unroll
  for (int k = 0; k < 16; k++) {
    int i = base + k * 256 + threadIdx.x;
    if (i < N_EDGES) atomicAdd(&h[dst[i] >> CB_SHIFT], 1);
  }
  __syncthreads();
  for (int i = threadIdx.x; i < NB_C; i += 256)
    if (h[i]) atomicAdd(&chist[i], h[i]);
}

__global__ void k_scan_coarse(const int* __restrict__ chist, int* __restrict__ cbase,
                              int* __restrict__ ccur) {
  if (threadIdx.x == 0 && blockIdx.x == 0) {
    int run = 0;
    #pragma unroll 1
    for (int b = 0; b < NB_C; b++) { cbase[b] = run; ccur[b] = run; run += chist[b]; }
    cbase[NB_C] = run;
  }
}

// P1: partition edges into coarse-bucket windows (packed u64 = src<<32 | dst)
__global__ __launch_bounds__(256)
void k_partition(const int* __restrict__ src, const int* __restrict__ dst,
                 int* __restrict__ ccur, u64* __restrict__ ebuf) {
  __shared__ int h[NB_C];
  __shared__ int bwin[NB_C];
  for (int i = threadIdx.x; i < NB_C; i += 256) h[i] = 0;
  __syncthreads();
  int base = blockIdx.x * 8192;
  int d[32];
  #pragma unroll
  for (int k = 0; k < 32; k++) {
    int i = base + k * 256 + threadIdx.x;
    d[k] = (i < N_EDGES) ? dst[i] : -1;
    if (d[k] >= 0) atomicAdd(&h[d[k] >> CB_SHIFT], 1);
  }
  __syncthreads();
  for (int i = threadIdx.x; i < NB_C; i += 256) {
    int c = h[i];
    bwin[i] = c ? atomicAdd(&ccur[i], c) : 0;
  }
  __syncthreads();
  for (int i = threadIdx.x; i < NB_C; i += 256) h[i] = 0;  // reuse as local cursor
  __syncthreads();
  #pragma unroll
  for (int k = 0; k < 32; k++) {
    if (d[k] >= 0) {
      int i = base + k * 256 + threadIdx.x;
      int b = d[k] >> CB_SHIFT;
      int loc = atomicAdd(&h[b], 1);
      ebuf[bwin[b] + loc] = ((u64)(unsigned)src[i] << 32) | (unsigned)d[k];
    }
  }
}

// P2a: per-bucket exact dst histogram -> counts (coalesced write; replaces k_count)
__global__ __launch_bounds__(256)
void k_bucket_hist(const u64* __restrict__ ebuf, const int* __restrict__ cbase,
                   int* __restrict__ counts) {
  __shared__ int h[CB_SIZE];
  int b = blockIdx.x;
  for (int i = threadIdx.x; i < CB_SIZE; i += 256) h[i] = 0;
  __syncthreads();
  int e1 = cbase[b + 1];
  for (int e = cbase[b] + threadIdx.x; e < e1; e += 256) {
    int dv = (int)(ebuf[e] & 0xFFFFFFFFull);
    atomicAdd(&h[dv & (CB_SIZE - 1)], 1);
  }
  __syncthreads();
  int n0 = b * CB_SIZE;
  for (int i = threadIdx.x; i < CB_SIZE; i += 256)
    if (n0 + i < N_NODES) counts[n0 + i] = h[i];
}

__global__ void k_dinv(const int* __restrict__ counts, float* __restrict__ dinv) {
  int i = blockIdx.x * 256 + threadIdx.x;
  if (i < N_NODES) dinv[i] = rsqrtf((float)(counts[i] + 1));  // +1 self-loop
}

__global__ void k_blocksums(const int* __restrict__ counts, int* __restrict__ bsums) {
  __shared__ int sd[256];
  int b = blockIdx.x, t = threadIdx.x;
  int i0 = b * 1024 + t * 4;
  int s = 0;
  #pragma unroll
  for (int i = 0; i < 4; i++) { int idx = i0 + i; if (idx < N_NODES) s += counts[idx]; }
  sd[t] = s;
  __syncthreads();
  for (int off = 128; off > 0; off >>= 1) {
    if (t < off) sd[t] += sd[t + off];
    __syncthreads();
  }
  if (t == 0) bsums[b] = sd[0];
}

__global__ void k_scan_bsums(const int* __restrict__ bsums, int* __restrict__ bbase) {
  if (threadIdx.x == 0 && blockIdx.x == 0) {
    int run = 0;
    #pragma unroll 1
    for (int b = 0; b < SCAN_NB; b++) { bbase[b] = run; run += bsums[b]; }
  }
}

__global__ void k_offsets(const int* __restrict__ counts, const int* __restrict__ bbase,
                          int* __restrict__ offsets) {
  __shared__ int ts[256];
  int b = blockIdx.x, t = threadIdx.x;
  int i0 = b * 1024 + t * 4;
  int loc[4];
  #pragma unroll
  for (int i = 0; i < 4; i++) { int idx = i0 + i; loc[i] = (idx < N_NODES) ? counts[idx] : 0; }
  int my = loc[0] + loc[1] + loc[2] + loc[3];
  ts[t] = my;
  __syncthreads();
  int v = my;
  for (int off = 1; off < 256; off <<= 1) {
    int y = (t >= off) ? ts[t - off] : 0;
    __syncthreads();
    v += y;
    ts[t] = v;
    __syncthreads();
  }
  int run = v - my + bbase[b];
  #pragma unroll
  for (int i = 0; i < 4; i++) {
    int idx = i0 + i;
    if (idx < N_NODES) offsets[idx] = run;
    run += loc[i];
  }
  if (b == 0 && t == 0) offsets[N_NODES] = N_EDGES;
}

// P2b: per-bucket scatter with LDS cursors; csr writes confined to bucket's ~32KB window
__global__ __launch_bounds__(256)
void k_scatter(const u64* __restrict__ ebuf, const int* __restrict__ cbase,
               const int* __restrict__ offsets, int* __restrict__ csr_src) {
  __shared__ int cur[CB_SIZE];
  int b = blockIdx.x;
  int n0 = b * CB_SIZE;
  for (int i = threadIdx.x; i < CB_SIZE; i += 256)
    cur[i] = (n0 + i < N_NODES) ? offsets[n0 + i] : 0;
  __syncthreads();
  int e1 = cbase[b + 1];
  for (int e = cbase[b] + threadIdx.x; e < e1; e += 256) {
    u64 p = ebuf[e];
    int dv = (int)(p & 0xFFFFFFFFull);
    int pos = atomicAdd(&cur[dv & (CB_SIZE - 1)], 1);
    csr_src[pos] = (int)(p >> 32);
  }
}

// ---------------- weight pre-pack (all 5 matrices, one kernel) ----------------
// Fragment for (ntile, ks): lane l holds B[k = ks*32 + (l>>4)*8 + j][col = ntile*16 + (l&15)]
// idx = ((ntile*ksteps + ks)*64 + lane)*8 + j

__device__ __forceinline__ void pack_one(const float* __restrict__ W, int K, int N, int t,
                                         u16* __restrict__ hi, u16* __restrict__ lo) {
  int k = t / N, n = t % N;
  unsigned hb, lb;
  bsplit(W[t], hb, lb);
  int nt = n >> 4, col = n & 15;
  int ks = k >> 5, kr = k & 31;
  int lane = (kr >> 3) * 16 + col;
  int j = kr & 7;
  int ksteps = K >> 5;
  size_t idx = (((size_t)(nt * ksteps + ks)) * 64 + lane) * 8 + j;
  hi[idx] = (u16)hb;
  lo[idx] = (u16)lb;
}

__global__ __launch_bounds__(256)
void k_pack_all(const float* __restrict__ W1, const float* __restrict__ W2,
                const float* __restrict__ Wf1, const float* __restrict__ Wf2,
                const float* __restrict__ Wf3,
                u16* pw1h, u16* pw1l, u16* pw2h, u16* pw2l,
                u16* p1h, u16* p1l, u16* p2h, u16* p2l, u16* p3h, u16* p3l) {
  int tid = blockIdx.x * 256 + threadIdx.x;
  if (tid < 8192)        pack_one(W1,  IN_DIM,  HID,     tid,          pw1h, pw1l);
  else if (tid < 12288)  pack_one(W2,  HID,     HID,     tid - 8192,   pw2h, pw2l);
  else if (tid < 28672)  pack_one(Wf1, HID,     MLP_HID, tid - 12288,  p1h,  p1l);
  else if (tid < 94208)  pack_one(Wf2, MLP_HID, MLP_HID, tid - 28672,  p2h,  p2l);
  else if (tid < 126976) pack_one(Wf3, MLP_HID, OUT_DIM, tid - 94208,  p3h,  p3l);
}

// ---------------- conv linear via split-bf16 MFMA: out[n] = (X[n] @ W) * dinv[n] -------------

template<int K>
__global__ __launch_bounds__(256, 2)
void k_conv(const float* __restrict__ X, const u16* __restrict__ wh, const u16* __restrict__ wl,
            const float* __restrict__ dinv, float* __restrict__ out) {
  constexpr int KS = K / 32;
  constexpr int STRIDE = K + 8;
  __shared__ u16 s_h[64][STRIDE];
  __shared__ u16 s_l[64][STRIDE];
  const int t = threadIdx.x;
  const int base = blockIdx.x * 64;

  const int tot4 = 64 * K / 4;
  for (int i = t; i < tot4; i += 256) {
    int f = i * 4;
    int r = f / K, c = f % K;
    int row = base + r;
    if (row >= N_NODES) row = N_NODES - 1;
    float4 v = *(const float4*)(X + (size_t)row * K + c);
    u16x4 h4, l4;
    unsigned hb, lb;
    bsplit(v.x, hb, lb); h4[0] = (u16)hb; l4[0] = (u16)lb;
    bsplit(v.y, hb, lb); h4[1] = (u16)hb; l4[1] = (u16)lb;
    bsplit(v.z, hb, lb); h4[2] = (u16)hb; l4[2] = (u16)lb;
    bsplit(v.w, hb, lb); h4[3] = (u16)hb; l4[3] = (u16)lb;
    *(u16x4*)&s_h[r][c] = h4;
    *(u16x4*)&s_l[r][c] = l4;
  }
  __syncthreads();

  const int w = t >> 6, lane = t & 63;
  const int lr = lane & 15;
  const int lg = lane >> 4;
  const int kofs = lg * 8;
  const int dr = lg * 4;

  fx4 acc[4];
  #pragma unroll
  for (int m = 0; m < 4; m++) acc[m] = (fx4){0.f, 0.f, 0.f, 0.f};

  #pragma unroll
  for (int ks = 0; ks < KS; ks++) {
    size_t fi = ((size_t)(w * KS + ks) * 64 + lane) * 8;
    bf16x8 bh = *(const bf16x8*)(wh + fi);
    bf16x8 bl = *(const bf16x8*)(wl + fi);
    #pragma unroll
    for (int m = 0; m < 4; m++) {
      bf16x8 ah = *(const bf16x8*)&s_h[m * 16 + lr][ks * 32 + kofs];
      bf16x8 al = *(const bf16x8*)&s_l[m * 16 + lr][ks * 32 + kofs];
      acc[m] = __builtin_amdgcn_mfma_f32_16x16x32_bf16(al, bh, acc[m], 0, 0, 0);
      acc[m] = __builtin_amdgcn_mfma_f32_16x16x32_bf16(ah, bl, acc[m], 0, 0, 0);
      acc[m] = __builtin_amdgcn_mfma_f32_16x16x32_bf16(ah, bh, acc[m], 0, 0, 0);
    }
  }

  #pragma unroll
  for (int m = 0; m < 4; m++)
    #pragma unroll
    for (int r = 0; r < 4; r++) {
      int row = base + m * 16 + dr + r;
      if (row < N_NODES)
        out[(size_t)row * 64 + w * 16 + lr] = acc[m][r] * dinv[row];
    }
}

// ---------------- aggregation: out[v] = ReLU(dinv[v]*(h'[v] + sum_s h'[s]) + b) --------------

__global__ __launch_bounds__(256)
void k_aggregate(const float* __restrict__ h, const int* __restrict__ offsets,
                 const int* __restrict__ csr_src, const float* __restrict__ dinv,
                 const float* __restrict__ bias, float* __restrict__ out) {
  int lane = threadIdx.x & 63;
  int wid = (blockIdx.x * 256 + threadIdx.x) >> 6;
  int nw = (gridDim.x * 256) >> 6;
  float bv = bias[lane];
  for (int v = wid; v < N_NODES; v += nw) {
    int e0 = offsets[v], e1 = offsets[v + 1];
    float acc = h[(size_t)v * 64 + lane];   // self-loop (pre-scaled)
    int e = e0;
    for (; e + 8 <= e1; e += 8) {
      int s0 = __builtin_amdgcn_readfirstlane(csr_src[e + 0]);
      int s1 = __builtin_amdgcn_readfirstlane(csr_src[e + 1]);
      int s2 = __builtin_amdgcn_readfirstlane(csr_src[e + 2]);
      int s3 = __builtin_amdgcn_readfirstlane(csr_src[e + 3]);
      int s4 = __builtin_amdgcn_readfirstlane(csr_src[e + 4]);
      int s5 = __builtin_amdgcn_readfirstlane(csr_src[e + 5]);
      int s6 = __builtin_amdgcn_readfirstlane(csr_src[e + 6]);
      int s7 = __builtin_amdgcn_readfirstlane(csr_src[e + 7]);
      float a0 = h[(size_t)s0 * 64 + lane];
      float a1 = h[(size_t)s1 * 64 + lane];
      float a2 = h[(size_t)s2 * 64 + lane];
      float a3 = h[(size_t)s3 * 64 + lane];
      float a4 = h[(size_t)s4 * 64 + lane];
      float a5 = h[(size_t)s5 * 64 + lane];
      float a6 = h[(size_t)s6 * 64 + lane];
      float a7 = h[(size_t)s7 * 64 + lane];
      acc += ((a0 + a1) + (a2 + a3)) + ((a4 + a5) + (a6 + a7));
    }
    for (; e < e1; e++) {
      int s = __builtin_amdgcn_readfirstlane(csr_src[e]);
      acc += h[(size_t)s * 64 + lane];
    }
    float r = acc * dinv[v] + bv;
    out[(size_t)v * 64 + lane] = r > 0.f ? r : 0.f;
  }
}

// ---------------- fused MLP via split-bf16 MFMA: 64 -> 256 -> 256 -> 128 ----------------

__global__ __launch_bounds__(256, 2)
void k_mlp(const float* __restrict__ X,
           const u16* __restrict__ w1h, const u16* __restrict__ w1l, const float* __restrict__ bb1,
           const u16* __restrict__ w2h, const u16* __restrict__ w2l, const float* __restrict__ bb2,
           const u16* __restrict__ w3h, const u16* __restrict__ w3l, const float* __restrict__ bb3,
           float* __restrict__ out) {
  __shared__ u16 s_h[64][264];
  __shared__ u16 s_l[64][264];
  const int t = threadIdx.x;
  const int w = t >> 6, lane = t & 63;
  const int base = blockIdx.x * 64;
  const int lr = lane & 15;
  const int lg = lane >> 4;
  const int kofs = lg * 8;
  const int dr = lg * 4;

  fx4 acc[4][4];

  // ---- Layer 1: 64 -> 256 (ksteps=2), A from global ----
  #pragma unroll
  for (int m = 0; m < 4; m++)
    #pragma unroll
    for (int n = 0; n < 4; n++) acc[m][n] = (fx4){0.f, 0.f, 0.f, 0.f};
  #pragma unroll
  for (int ks = 0; ks < 2; ks++) {
    bf16x8 ah[4], al[4];
    #pragma unroll
    for (int m = 0; m < 4; m++) {
      int row = base + m * 16 + lr;
      if (row >= N_NODES) row = N_NODES - 1;
      split8(X + (size_t)row * 64 + ks * 32 + kofs, ah[m], al[m]);
    }
    #pragma unroll
    for (int n = 0; n < 4; n++) {
      size_t fi = ((size_t)((w * 4 + n) * 2 + ks) * 64 + lane) * 8;
      bf16x8 bh = *(const bf16x8*)(w1h + fi);
      bf16x8 bl = *(const bf16x8*)(w1l + fi);
      #pragma unroll
      for (int m = 0; m < 4; m++) {
        acc[m][n] = __builtin_amdgcn_mfma_f32_16x16x32_bf16(al[m], bh, acc[m][n], 0, 0, 0);
        acc[m][n] = __builtin_amdgcn_mfma_f32_16x16x32_bf16(ah[m], bl, acc[m][n], 0, 0, 0);
        acc[m][n] = __builtin_amdgcn_mfma_f32_16x16x32_bf16(ah[m], bh, acc[m][n], 0, 0, 0);
      }
    }
  }
  #pragma unroll
  for (int n = 0; n < 4; n++) {
    float bias = bb1[(w * 4 + n) * 16 + lr];
    #pragma unroll
    for (int m = 0; m < 4; m++)
      #pragma unroll
      for (int r = 0; r < 4; r++) {
        float v = acc[m][n][r] + bias;
        v = v > 0.f ? v : 0.f;
        unsigned hb, lb;
        bsplit(v, hb, lb);
        s_h[m * 16 + dr + r][(w * 4 + n) * 16 + lr] = (u16)hb;
        s_l[m * 16 + dr + r][(w * 4 + n) * 16 + lr] = (u16)lb;
      }
  }
  __syncthreads();

  // ---- Layer 2: 256 -> 256 (ksteps=8) ----
  #pragma unroll
  for (int m = 0; m < 4; m++)
    #pragma unroll
    for (int n = 0; n < 4; n++) acc[m][n] = (fx4){0.f, 0.f, 0.f, 0.f};
  for (int ks = 0; ks < 8; ks++) {
    bf16x8 ah[4], al[4];
    #pragma unroll
    for (int m = 0; m < 4; m++) {
      ah[m] = *(const bf16x8*)&s_h[m * 16 + lr][ks * 32 + kofs];
      al[m] = *(const bf16x8*)&s_l[m * 16 + lr][ks * 32 + kofs];
    }
    #pragma unroll
    for (int n = 0; n < 4; n++) {
      size_t fi = ((size_t)((w * 4 + n) * 8 + ks) * 64 + lane) * 8;
      bf16x8 bh = *(const bf16x8*)(w2h + fi);
      bf16x8 bl = *(const bf16x8*)(w2l + fi);
      #pragma unroll
      for (int m = 0; m < 4; m++) {
        acc[m][n] = __builtin_amdgcn_mfma_f32_16x16x32_bf16(al[m], bh, acc[m][n], 0, 0, 0);
        acc[m][n] = __builtin_amdgcn_mfma_f32_16x16x32_bf16(ah[m], bl, acc[m][n], 0, 0, 0);
        acc[m][n] = __builtin_amdgcn_mfma_f32_16x16x32_bf16(ah[m], bh, acc[m][n], 0, 0, 0);
      }
    }
  }
  __syncthreads();
  #pragma unroll
  for (int n = 0; n < 4; n++) {
    float bias = bb2[(w * 4 + n) * 16 + lr];
    #pragma unroll
    for (int m = 0; m < 4; m++)
      #pragma unroll
      for (int r = 0; r < 4; r++) {
        float v = acc[m][n][r] + bias;
        v = v > 0.f ? v : 0.f;
        unsigned hb, lb;
        bsplit(v, hb, lb);
        s_h[m * 16 + dr + r][(w * 4 + n) * 16 + lr] = (u16)hb;
        s_l[m * 16 + dr + r][(w * 4 + n) * 16 + lr] = (u16)lb;
      }
  }
  __syncthreads();

  // ---- Layer 3: 256 -> 128 (ksteps=8), 2 n-tiles per wave ----
  fx4 a3[4][2];
  #pragma unroll
  for (int m = 0; m < 4; m++)
    #pragma unroll
    for (int i = 0; i < 2; i++) a3[m][i] = (fx4){0.f, 0.f, 0.f, 0.f};
  for (int ks = 0; ks < 8; ks++) {
    bf16x8 ah[4], al[4];
    #pragma unroll
    for (int m = 0; m < 4; m++) {
      ah[m] = *(const bf16x8*)&s_h[m * 16 + lr][ks * 32 + kofs];
      al[m] = *(const bf16x8*)&s_l[m * 16 + lr][ks * 32 + kofs];
    }
    #pragma unroll
    for (int i = 0; i < 2; i++) {
      size_t fi = ((size_t)((w * 2 + i) * 8 + ks) * 64 + lane) * 8;
      bf16x8 bh = *(const bf16x8*)(w3h + fi);
      bf16x8 bl = *(const bf16x8*)(w3l + fi);
      #pragma unroll
      for (int m = 0; m < 4; m++) {
        a3[m][i] = __builtin_amdgcn_mfma_f32_16x16x32_bf16(al[m], bh, a3[m][i], 0, 0, 0);
        a3[m][i] = __builtin_amdgcn_mfma_f32_16x16x32_bf16(ah[m], bl, a3[m][i], 0, 0, 0);
        a3[m][i] = __builtin_amdgcn_mfma_f32_16x16x32_bf16(ah[m], bh, a3[m][i], 0, 0, 0);
      }
    }
  }
  #pragma unroll
  for (int i = 0; i < 2; i++) {
    int col = (w * 2 + i) * 16 + lr;
    float bias = bb3[col];
    #pragma unroll
    for (int m = 0; m < 4; m++)
      #pragma unroll
      for (int r = 0; r < 4; r++) {
        int row = base + m * 16 + dr + r;
        if (row < N_NODES) {
          float v = a3[m][i][r] + bias;
          out[(size_t)row * 128 + col] = v > 0.f ? v : 0.f;
        }
      }
  }
}

// ---------------- launch ----------------

extern "C" void kernel_launch(void* const* d_in, const int* in_sizes, int n_in,
                              void* d_out, int out_size, void* d_ws, size_t ws_size,
                              hipStream_t stream) {
  const float* x   = (const float*)d_in[0];
  const int*   ei  = (const int*)d_in[1];
  const float* W1  = (const float*)d_in[2];
  const float* b1  = (const float*)d_in[3];
  const float* W2  = (const float*)d_in[4];
  const float* b2  = (const float*)d_in[5];
  const float* Wf1 = (const float*)d_in[6];
  const float* bf1 = (const float*)d_in[7];
  const float* Wf2 = (const float*)d_in[8];
  const float* bf2 = (const float*)d_in[9];
  const float* Wf3 = (const float*)d_in[10];
  const float* bf3 = (const float*)d_in[11];
  float* out = (float*)d_out;

  const int* src = ei;             // edge_index[0]
  const int* dst = ei + N_EDGES;   // edge_index[1]

  // workspace layout (16B-aligned chunks)
  int*   chist   = (int*)d_ws;           // 256
  int*   cbase   = chist + 256;          // 256 (NB_C+1 used)
  int*   ccur    = cbase + 256;          // 256
  int*   offsets = ccur + 256;           // 100352+16
  int*   bsums   = offsets + 100368;     // 256
  int*   bbase   = bsums + 256;          // 256
  int*   counts  = bbase + 256;          // 100352
  int*   csr_src = counts + 100352;      // E
  float* dinv    = (float*)(csr_src + N_EDGES);
  float* bufA    = dinv + 100352;
  float* bufB    = bufA + N_NODES * HID;
  u16*   p1h     = (u16*)(bufB + N_NODES * HID);
  u16*   p1l     = p1h + HID * MLP_HID;
  u16*   p2h     = p1l + HID * MLP_HID;
  u16*   p2l     = p2h + MLP_HID * MLP_HID;
  u16*   p3h     = p2l + MLP_HID * MLP_HID;
  u16*   p3l     = p3h + MLP_HID * OUT_DIM;
  u16*   pw1h    = p3l + MLP_HID * OUT_DIM;
  u16*   pw1l    = pw1h + IN_DIM * HID;
  u16*   pw2h    = pw1l + IN_DIM * HID;
  u16*   pw2l    = pw2h + HID * HID;
  u64*   ebuf    = (u64*)bufA;           // aliased: dead before conv1 writes bufA

  hipMemsetAsync(chist, 0, 256 * sizeof(int), stream);

  k_coarse_hist<<<391, 256, 0, stream>>>(dst, chist);
  k_scan_coarse<<<1, 64, 0, stream>>>(chist, cbase, ccur);
  k_partition  <<<196, 256, 0, stream>>>(src, dst, ccur, ebuf);
  k_bucket_hist<<<NB_C, 256, 0, stream>>>(ebuf, cbase, counts);
  k_dinv       <<<(N_NODES + 255) / 256, 256, 0, stream>>>(counts, dinv);
  k_blocksums  <<<SCAN_NB, 256, 0, stream>>>(counts, bsums);
  k_scan_bsums <<<1, 64, 0, stream>>>(bsums, bbase);
  k_offsets    <<<SCAN_NB, 256, 0, stream>>>(counts, bbase, offsets);
  k_scatter    <<<NB_C, 256, 0, stream>>>(ebuf, cbase, offsets, csr_src);

  k_pack_all<<<496, 256, 0, stream>>>(W1, W2, Wf1, Wf2, Wf3,
                                      pw1h, pw1l, pw2h, pw2l,
                                      p1h, p1l, p2h, p2l, p3h, p3l);

  k_conv<IN_DIM><<<(N_NODES + 63) / 64, 256, 0, stream>>>(x, pw1h, pw1l, dinv, bufA);
  k_aggregate   <<<4096, 256, 0, stream>>>(bufA, offsets, csr_src, dinv, b1, bufB);
  k_conv<HID>   <<<(N_NODES + 63) / 64, 256, 0, stream>>>(bufB, pw2h, pw2l, dinv, bufA);
  k_aggregate   <<<4096, 256, 0, stream>>>(bufA, offsets, csr_src, dinv, b2, bufB);

  k_mlp<<<(N_NODES + 63) / 64, 256, 0, stream>>>(bufB, p1h, p1l, bf1, p2h, p2l, bf2,
                                                 p3h, p3l, bf3, out);
}

// Round 6
// 480.033 us; speedup vs baseline: 2.3073x; 1.0606x over previous
//
#include <hip/hip_runtime.h>

#define N_NODES 100000
#define N_EDGES 1600000
#define IN_DIM  128
#define HID     64
#define MLP_HID 256
#define OUT_DIM 128

#define CB_SHIFT 9
#define CB_SIZE  512
#define NB_C     196  // ceil(100000/512)

typedef __attribute__((ext_vector_type(4))) float fx4;
typedef __attribute__((ext_vector_type(8))) short bf16x8;
typedef __attribute__((ext_vector_type(4))) unsigned short u16x4;
typedef unsigned short u16;

// ---------------- bf16 hi/lo split helpers ----------------

__device__ __forceinline__ void bsplit(float x, unsigned& hb, unsigned& lb) {
  unsigned u = __float_as_uint(x);
  hb = (u + 0x7FFFu + ((u >> 16) & 1u)) >> 16;           // RNE to bf16
  float rl = x - __uint_as_float(hb << 16);              // exact residual
  unsigned ul = __float_as_uint(rl);
  lb = (ul + 0x7FFFu + ((ul >> 16) & 1u)) >> 16;
}

__device__ __forceinline__ void split8(const float* p, bf16x8& ah, bf16x8& al) {
  float4 f0 = *(const float4*)p;
  float4 f1 = *(const float4*)(p + 4);
  float f[8] = {f0.x, f0.y, f0.z, f0.w, f1.x, f1.y, f1.z, f1.w};
  #pragma unroll
  for (int j = 0; j < 8; j++) {
    unsigned hb, lb;
    bsplit(f[j], hb, lb);
    ah[j] = (short)hb;
    al[j] = (short)lb;
  }
}

// ---------------- graph build: bucketed counting sort ----------------

// P0: coarse histogram of dst>>9
__global__ __launch_bounds__(256)
void k_coarse_hist(const int* __restrict__ dst, int* __restrict__ chist) {
  __shared__ int h[NB_C];
  for (int i = threadIdx.x; i < NB_C; i += 256) h[i] = 0;
  __syncthreads();
  int base = blockIdx.x * 4096;
  #pragma unroll
  for (int k = 0; k < 16; k++) {
    int i = base + k * 256 + threadIdx.x;
    if (i < N_EDGES) atomicAdd(&h[dst[i] >> CB_SHIFT], 1);
  }
  __syncthreads();
  for (int i = threadIdx.x; i < NB_C; i += 256)
    if (h[i]) atomicAdd(&chist[i], h[i]);
}

__global__ void k_scan_coarse(const int* __restrict__ chist, int* __restrict__ cbase,
                              int* __restrict__ ccur) {
  if (threadIdx.x == 0 && blockIdx.x == 0) {
    int run = 0;
    #pragma unroll 1
    for (int b = 0; b < NB_C; b++) { cbase[b] = run; ccur[b] = run; run += chist[b]; }
    cbase[NB_C] = run;
  }
}

// P1: partition edges into coarse-bucket windows, packed u32 = src<<9 | dst_low9
__global__ __launch_bounds__(256)
void k_partition(const int* __restrict__ src, const int* __restrict__ dst,
                 int* __restrict__ ccur, unsigned* __restrict__ ebuf) {
  __shared__ int h[NB_C];
  __shared__ int bwin[NB_C];
  for (int i = threadIdx.x; i < NB_C; i += 256) h[i] = 0;
  __syncthreads();
  int base = blockIdx.x * 8192;
  int d[32];
  #pragma unroll
  for (int k = 0; k < 32; k++) {
    int i = base + k * 256 + threadIdx.x;
    d[k] = (i < N_EDGES) ? dst[i] : -1;
    if (d[k] >= 0) atomicAdd(&h[d[k] >> CB_SHIFT], 1);
  }
  __syncthreads();
  for (int i = threadIdx.x; i < NB_C; i += 256) {
    int c = h[i];
    bwin[i] = c ? atomicAdd(&ccur[i], c) : 0;
  }
  __syncthreads();
  for (int i = threadIdx.x; i < NB_C; i += 256) h[i] = 0;  // reuse as local cursor
  __syncthreads();
  #pragma unroll
  for (int k = 0; k < 32; k++) {
    if (d[k] >= 0) {
      int i = base + k * 256 + threadIdx.x;
      int b = d[k] >> CB_SHIFT;
      int loc = atomicAdd(&h[b], 1);
      ebuf[bwin[b] + loc] = ((unsigned)src[i] << CB_SHIFT) | (unsigned)(d[k] & (CB_SIZE - 1));
    }
  }
}

// P2a: per-bucket hist + scan -> CSR offsets + dinv directly
// (bucket b owns nodes [b*512,(b+1)*512) and edge window [cbase[b],cbase[b+1]))
__global__ __launch_bounds__(256)
void k_bucket_offsets(const unsigned* __restrict__ ebuf, const int* __restrict__ cbase,
                      int* __restrict__ offsets, float* __restrict__ dinv) {
  __shared__ int h[CB_SIZE];
  __shared__ int ts[256];
  int b = blockIdx.x, t = threadIdx.x;
  for (int i = t; i < CB_SIZE; i += 256) h[i] = 0;
  __syncthreads();
  int w0 = cbase[b], e1 = cbase[b + 1];
  for (int e = w0 + t; e < e1; e += 256)
    atomicAdd(&h[ebuf[e] & (CB_SIZE - 1)], 1);
  __syncthreads();
  int n0 = b * CB_SIZE;
  int c0 = h[2 * t], c1 = h[2 * t + 1];
  // dinv
  if (n0 + 2 * t     < N_NODES) dinv[n0 + 2 * t]     = rsqrtf((float)(c0 + 1));
  if (n0 + 2 * t + 1 < N_NODES) dinv[n0 + 2 * t + 1] = rsqrtf((float)(c1 + 1));
  // scan pairs
  int my = c0 + c1;
  ts[t] = my;
  __syncthreads();
  int v = my;
  for (int off = 1; off < 256; off <<= 1) {
    int y = (t >= off) ? ts[t - off] : 0;
    __syncthreads();
    v += y;
    ts[t] = v;
    __syncthreads();
  }
  int excl = w0 + v - my;
  if (n0 + 2 * t     < N_NODES) offsets[n0 + 2 * t]     = excl;
  if (n0 + 2 * t + 1 < N_NODES) offsets[n0 + 2 * t + 1] = excl + c0;
  if (b == NB_C - 1 && t == 0) offsets[N_NODES] = N_EDGES;
}

// P2b: per-bucket scatter with LDS cursors; csr writes confined to bucket window
__global__ __launch_bounds__(256)
void k_scatter(const unsigned* __restrict__ ebuf, const int* __restrict__ cbase,
               const int* __restrict__ offsets, int* __restrict__ csr_src) {
  __shared__ int cur[CB_SIZE];
  int b = blockIdx.x;
  int n0 = b * CB_SIZE;
  for (int i = threadIdx.x; i < CB_SIZE; i += 256)
    cur[i] = (n0 + i < N_NODES) ? offsets[n0 + i] : 0;
  __syncthreads();
  int e1 = cbase[b + 1];
  for (int e = cbase[b] + threadIdx.x; e < e1; e += 256) {
    unsigned p = ebuf[e];
    int pos = atomicAdd(&cur[p & (CB_SIZE - 1)], 1);
    csr_src[pos] = (int)(p >> CB_SHIFT);
  }
}

// ---------------- weight pre-pack (all 5 matrices, one kernel) ----------------
// Fragment for (ntile, ks): lane l holds B[k = ks*32 + (l>>4)*8 + j][col = ntile*16 + (l&15)]
// idx = ((ntile*ksteps + ks)*64 + lane)*8 + j

__device__ __forceinline__ void pack_one(const float* __restrict__ W, int K, int N, int t,
                                         u16* __restrict__ hi, u16* __restrict__ lo) {
  int k = t / N, n = t % N;
  unsigned hb, lb;
  bsplit(W[t], hb, lb);
  int nt = n >> 4, col = n & 15;
  int ks = k >> 5, kr = k & 31;
  int lane = (kr >> 3) * 16 + col;
  int j = kr & 7;
  int ksteps = K >> 5;
  size_t idx = (((size_t)(nt * ksteps + ks)) * 64 + lane) * 8 + j;
  hi[idx] = (u16)hb;
  lo[idx] = (u16)lb;
}

__global__ __launch_bounds__(256)
void k_pack_all(const float* __restrict__ W1, const float* __restrict__ W2,
                const float* __restrict__ Wf1, const float* __restrict__ Wf2,
                const float* __restrict__ Wf3,
                u16* pw1h, u16* pw1l, u16* pw2h, u16* pw2l,
                u16* p1h, u16* p1l, u16* p2h, u16* p2l, u16* p3h, u16* p3l) {
  int tid = blockIdx.x * 256 + threadIdx.x;
  if (tid < 8192)        pack_one(W1,  IN_DIM,  HID,     tid,          pw1h, pw1l);
  else if (tid < 12288)  pack_one(W2,  HID,     HID,     tid - 8192,   pw2h, pw2l);
  else if (tid < 28672)  pack_one(Wf1, HID,     MLP_HID, tid - 12288,  p1h,  p1l);
  else if (tid < 94208)  pack_one(Wf2, MLP_HID, MLP_HID, tid - 28672,  p2h,  p2l);
  else if (tid < 126976) pack_one(Wf3, MLP_HID, OUT_DIM, tid - 94208,  p3h,  p3l);
}

// ---------------- conv linear via split-bf16 MFMA: out[n] = (X[n] @ W) * dinv[n] -------------
// 512 threads = 8 waves, 64 nodes/block. wave w: m-pair = w>>2, n-tile = w&3.

template<int K>
__global__ __launch_bounds__(512, 4)
void k_conv(const float* __restrict__ X, const u16* __restrict__ wh, const u16* __restrict__ wl,
            const float* __restrict__ dinv, float* __restrict__ out) {
  constexpr int KS = K / 32;
  constexpr int STRIDE = K + 8;
  __shared__ u16 s_h[64][STRIDE];
  __shared__ u16 s_l[64][STRIDE];
  const int t = threadIdx.x;
  const int base = blockIdx.x * 64;

  const int tot4 = 64 * K / 4;
  for (int i = t; i < tot4; i += 512) {
    int f = i * 4;
    int r = f / K, c = f % K;
    int row = base + r;
    if (row >= N_NODES) row = N_NODES - 1;
    float4 v = *(const float4*)(X + (size_t)row * K + c);
    u16x4 h4, l4;
    unsigned hb, lb;
    bsplit(v.x, hb, lb); h4[0] = (u16)hb; l4[0] = (u16)lb;
    bsplit(v.y, hb, lb); h4[1] = (u16)hb; l4[1] = (u16)lb;
    bsplit(v.z, hb, lb); h4[2] = (u16)hb; l4[2] = (u16)lb;
    bsplit(v.w, hb, lb); h4[3] = (u16)hb; l4[3] = (u16)lb;
    *(u16x4*)&s_h[r][c] = h4;
    *(u16x4*)&s_l[r][c] = l4;
  }
  __syncthreads();

  const int w = t >> 6, lane = t & 63;
  const int mg = w >> 2;        // m-pair: m-tiles {2mg, 2mg+1}
  const int nt = w & 3;
  const int lr = lane & 15;
  const int lg = lane >> 4;
  const int kofs = lg * 8;
  const int dr = lg * 4;

  fx4 acc[2];
  #pragma unroll
  for (int m = 0; m < 2; m++) acc[m] = (fx4){0.f, 0.f, 0.f, 0.f};

  #pragma unroll
  for (int ks = 0; ks < KS; ks++) {
    size_t fi = ((size_t)(nt * KS + ks) * 64 + lane) * 8;
    bf16x8 bh = *(const bf16x8*)(wh + fi);
    bf16x8 bl = *(const bf16x8*)(wl + fi);
    #pragma unroll
    for (int m = 0; m < 2; m++) {
      int mrow = (mg * 2 + m) * 16 + lr;
      bf16x8 ah = *(const bf16x8*)&s_h[mrow][ks * 32 + kofs];
      bf16x8 al = *(const bf16x8*)&s_l[mrow][ks * 32 + kofs];
      acc[m] = __builtin_amdgcn_mfma_f32_16x16x32_bf16(al, bh, acc[m], 0, 0, 0);
      acc[m] = __builtin_amdgcn_mfma_f32_16x16x32_bf16(ah, bl, acc[m], 0, 0, 0);
      acc[m] = __builtin_amdgcn_mfma_f32_16x16x32_bf16(ah, bh, acc[m], 0, 0, 0);
    }
  }

  #pragma unroll
  for (int m = 0; m < 2; m++)
    #pragma unroll
    for (int r = 0; r < 4; r++) {
      int row = base + (mg * 2 + m) * 16 + dr + r;
      if (row < N_NODES)
        out[(size_t)row * 64 + nt * 16 + lr] = acc[m][r] * dinv[row];
    }
}

// ---------------- aggregation: out[v] = ReLU(dinv[v]*(h'[v] + sum_s h'[s]) + b) --------------

__global__ __launch_bounds__(256)
void k_aggregate(const float* __restrict__ h, const int* __restrict__ offsets,
                 const int* __restrict__ csr_src, const float* __restrict__ dinv,
                 const float* __restrict__ bias, float* __restrict__ out) {
  int lane = threadIdx.x & 63;
  int wid = (blockIdx.x * 256 + threadIdx.x) >> 6;
  int nw = (gridDim.x * 256) >> 6;
  float bv = bias[lane];
  for (int v = wid; v < N_NODES; v += nw) {
    int e0 = offsets[v], e1 = offsets[v + 1];
    float acc = h[(size_t)v * 64 + lane];   // self-loop (pre-scaled)
    int e = e0;
    for (; e + 8 <= e1; e += 8) {
      int s0 = __builtin_amdgcn_readfirstlane(csr_src[e + 0]);
      int s1 = __builtin_amdgcn_readfirstlane(csr_src[e + 1]);
      int s2 = __builtin_amdgcn_readfirstlane(csr_src[e + 2]);
      int s3 = __builtin_amdgcn_readfirstlane(csr_src[e + 3]);
      int s4 = __builtin_amdgcn_readfirstlane(csr_src[e + 4]);
      int s5 = __builtin_amdgcn_readfirstlane(csr_src[e + 5]);
      int s6 = __builtin_amdgcn_readfirstlane(csr_src[e + 6]);
      int s7 = __builtin_amdgcn_readfirstlane(csr_src[e + 7]);
      float a0 = h[(size_t)s0 * 64 + lane];
      float a1 = h[(size_t)s1 * 64 + lane];
      float a2 = h[(size_t)s2 * 64 + lane];
      float a3 = h[(size_t)s3 * 64 + lane];
      float a4 = h[(size_t)s4 * 64 + lane];
      float a5 = h[(size_t)s5 * 64 + lane];
      float a6 = h[(size_t)s6 * 64 + lane];
      float a7 = h[(size_t)s7 * 64 + lane];
      acc += ((a0 + a1) + (a2 + a3)) + ((a4 + a5) + (a6 + a7));
    }
    for (; e < e1; e++) {
      int s = __builtin_amdgcn_readfirstlane(csr_src[e]);
      acc += h[(size_t)s * 64 + lane];
    }
    float r = acc * dinv[v] + bv;
    out[(size_t)v * 64 + lane] = r > 0.f ? r : 0.f;
  }
}

// ---------------- fused MLP via split-bf16 MFMA: 64 -> 256 -> 256 -> 128 ----------------
// 512 threads = 8 waves, 64 nodes/block. Waves split N: 2 tiles each (L1/L2), 1 tile (L3).

__global__ __launch_bounds__(512, 4)
void k_mlp(const float* __restrict__ X,
           const u16* __restrict__ w1h, const u16* __restrict__ w1l, const float* __restrict__ bb1,
           const u16* __restrict__ w2h, const u16* __restrict__ w2l, const float* __restrict__ bb2,
           const u16* __restrict__ w3h, const u16* __restrict__ w3l, const float* __restrict__ bb3,
           float* __restrict__ out) {
  __shared__ u16 s_h[64][264];
  __shared__ u16 s_l[64][264];
  const int t = threadIdx.x;
  const int w = t >> 6, lane = t & 63;
  const int base = blockIdx.x * 64;
  const int lr = lane & 15;
  const int lg = lane >> 4;
  const int kofs = lg * 8;
  const int dr = lg * 4;

  fx4 acc[4][2];

  // ---- Layer 1: 64 -> 256 (ksteps=2), A from global; wave w -> n-tiles {2w, 2w+1} ----
  #pragma unroll
  for (int m = 0; m < 4; m++)
    #pragma unroll
    for (int n = 0; n < 2; n++) acc[m][n] = (fx4){0.f, 0.f, 0.f, 0.f};
  #pragma unroll
  for (int ks = 0; ks < 2; ks++) {
    bf16x8 ah[4], al[4];
    #pragma unroll
    for (int m = 0; m < 4; m++) {
      int row = base + m * 16 + lr;
      if (row >= N_NODES) row = N_NODES - 1;
      split8(X + (size_t)row * 64 + ks * 32 + kofs, ah[m], al[m]);
    }
    #pragma unroll
    for (int n = 0; n < 2; n++) {
      size_t fi = ((size_t)((w * 2 + n) * 2 + ks) * 64 + lane) * 8;
      bf16x8 bh = *(const bf16x8*)(w1h + fi);
      bf16x8 bl = *(const bf16x8*)(w1l + fi);
      #pragma unroll
      for (int m = 0; m < 4; m++) {
        acc[m][n] = __builtin_amdgcn_mfma_f32_16x16x32_bf16(al[m], bh, acc[m][n], 0, 0, 0);
        acc[m][n] = __builtin_amdgcn_mfma_f32_16x16x32_bf16(ah[m], bl, acc[m][n], 0, 0, 0);
        acc[m][n] = __builtin_amdgcn_mfma_f32_16x16x32_bf16(ah[m], bh, acc[m][n], 0, 0, 0);
      }
    }
  }
  #pragma unroll
  for (int n = 0; n < 2; n++) {
    int nt = w * 2 + n;
    float bias = bb1[nt * 16 + lr];
    #pragma unroll
    for (int m = 0; m < 4; m++)
      #pragma unroll
      for (int r = 0; r < 4; r++) {
        float v = acc[m][n][r] + bias;
        v = v > 0.f ? v : 0.f;
        unsigned hb, lb;
        bsplit(v, hb, lb);
        s_h[m * 16 + dr + r][nt * 16 + lr] = (u16)hb;
        s_l[m * 16 + dr + r][nt * 16 + lr] = (u16)lb;
      }
  }
  __syncthreads();

  // ---- Layer 2: 256 -> 256 (ksteps=8); wave w -> n-tiles {2w, 2w+1} ----
  #pragma unroll
  for (int m = 0; m < 4; m++)
    #pragma unroll
    for (int n = 0; n < 2; n++) acc[m][n] = (fx4){0.f, 0.f, 0.f, 0.f};
  for (int ks = 0; ks < 8; ks++) {
    bf16x8 ah[4], al[4];
    #pragma unroll
    for (int m = 0; m < 4; m++) {
      ah[m] = *(const bf16x8*)&s_h[m * 16 + lr][ks * 32 + kofs];
      al[m] = *(const bf16x8*)&s_l[m * 16 + lr][ks * 32 + kofs];
    }
    #pragma unroll
    for (int n = 0; n < 2; n++) {
      size_t fi = ((size_t)((w * 2 + n) * 8 + ks) * 64 + lane) * 8;
      bf16x8 bh = *(const bf16x8*)(w2h + fi);
      bf16x8 bl = *(const bf16x8*)(w2l + fi);
      #pragma unroll
      for (int m = 0; m < 4; m++) {
        acc[m][n] = __builtin_amdgcn_mfma_f32_16x16x32_bf16(al[m], bh, acc[m][n], 0, 0, 0);
        acc[m][n] = __builtin_amdgcn_mfma_f32_16x16x32_bf16(ah[m], bl, acc[m][n], 0, 0, 0);
        acc[m][n] = __builtin_amdgcn_mfma_f32_16x16x32_bf16(ah[m], bh, acc[m][n], 0, 0, 0);
      }
    }
  }
  __syncthreads();
  #pragma unroll
  for (int n = 0; n < 2; n++) {
    int nt = w * 2 + n;
    float bias = bb2[nt * 16 + lr];
    #pragma unroll
    for (int m = 0; m < 4; m++)
      #pragma unroll
      for (int r = 0; r < 4; r++) {
        float v = acc[m][n][r] + bias;
        v = v > 0.f ? v : 0.f;
        unsigned hb, lb;
        bsplit(v, hb, lb);
        s_h[m * 16 + dr + r][nt * 16 + lr] = (u16)hb;
        s_l[m * 16 + dr + r][nt * 16 + lr] = (u16)lb;
      }
  }
  __syncthreads();

  // ---- Layer 3: 256 -> 128 (ksteps=8); wave w -> n-tile w ----
  fx4 a3[4];
  #pragma unroll
  for (int m = 0; m < 4; m++) a3[m] = (fx4){0.f, 0.f, 0.f, 0.f};
  for (int ks = 0; ks < 8; ks++) {
    size_t fi = ((size_t)(w * 8 + ks) * 64 + lane) * 8;
    bf16x8 bh = *(const bf16x8*)(w3h + fi);
    bf16x8 bl = *(const bf16x8*)(w3l + fi);
    #pragma unroll
    for (int m = 0; m < 4; m++) {
      bf16x8 ah = *(const bf16x8*)&s_h[m * 16 + lr][ks * 32 + kofs];
      bf16x8 al = *(const bf16x8*)&s_l[m * 16 + lr][ks * 32 + kofs];
      a3[m] = __builtin_amdgcn_mfma_f32_16x16x32_bf16(al, bh, a3[m], 0, 0, 0);
      a3[m] = __builtin_amdgcn_mfma_f32_16x16x32_bf16(ah, bl, a3[m], 0, 0, 0);
      a3[m] = __builtin_amdgcn_mfma_f32_16x16x32_bf16(ah, bh, a3[m], 0, 0, 0);
    }
  }
  {
    int col = w * 16 + lr;
    float bias = bb3[col];
    #pragma unroll
    for (int m = 0; m < 4; m++)
      #pragma unroll
      for (int r = 0; r < 4; r++) {
        int row = base + m * 16 + dr + r;
        if (row < N_NODES) {
          float v = a3[m][r] + bias;
          out[(size_t)row * 128 + col] = v > 0.f ? v : 0.f;
        }
      }
  }
}

// ---------------- launch ----------------

extern "C" void kernel_launch(void* const* d_in, const int* in_sizes, int n_in,
                              void* d_out, int out_size, void* d_ws, size_t ws_size,
                              hipStream_t stream) {
  const float* x   = (const float*)d_in[0];
  const int*   ei  = (const int*)d_in[1];
  const float* W1  = (const float*)d_in[2];
  const float* b1  = (const float*)d_in[3];
  const float* W2  = (const float*)d_in[4];
  const float* b2  = (const float*)d_in[5];
  const float* Wf1 = (const float*)d_in[6];
  const float* bf1 = (const float*)d_in[7];
  const float* Wf2 = (const float*)d_in[8];
  const float* bf2 = (const float*)d_in[9];
  const float* Wf3 = (const float*)d_in[10];
  const float* bf3 = (const float*)d_in[11];
  float* out = (float*)d_out;

  const int* src = ei;             // edge_index[0]
  const int* dst = ei + N_EDGES;   // edge_index[1]

  // workspace layout (16B-aligned chunks)
  int*      chist   = (int*)d_ws;           // 256
  int*      cbase   = chist + 256;          // 256 (NB_C+1 used)
  int*      ccur    = cbase + 256;          // 256
  int*      offsets = ccur + 256;           // 100352+16
  int*      csr_src = offsets + 100368;     // E
  float*    dinv    = (float*)(csr_src + N_EDGES);
  float*    bufA    = dinv + 100352;
  float*    bufB    = bufA + N_NODES * HID;
  u16*      p1h     = (u16*)(bufB + N_NODES * HID);
  u16*      p1l     = p1h + HID * MLP_HID;
  u16*      p2h     = p1l + HID * MLP_HID;
  u16*      p2l     = p2h + MLP_HID * MLP_HID;
  u16*      p3h     = p2l + MLP_HID * MLP_HID;
  u16*      p3l     = p3h + MLP_HID * OUT_DIM;
  u16*      pw1h    = p3l + MLP_HID * OUT_DIM;
  u16*      pw1l    = pw1h + IN_DIM * HID;
  u16*      pw2h    = pw1l + IN_DIM * HID;
  u16*      pw2l    = pw2h + HID * HID;
  unsigned* ebuf    = (unsigned*)bufA;      // aliased: dead before conv1 writes bufA

  hipMemsetAsync(chist, 0, 256 * sizeof(int), stream);

  k_coarse_hist   <<<391, 256, 0, stream>>>(dst, chist);
  k_scan_coarse   <<<1, 64, 0, stream>>>(chist, cbase, ccur);
  k_partition     <<<196, 256, 0, stream>>>(src, dst, ccur, ebuf);
  k_bucket_offsets<<<NB_C, 256, 0, stream>>>(ebuf, cbase, offsets, dinv);
  k_scatter       <<<NB_C, 256, 0, stream>>>(ebuf, cbase, offsets, csr_src);

  k_pack_all<<<496, 256, 0, stream>>>(W1, W2, Wf1, Wf2, Wf3,
                                      pw1h, pw1l, pw2h, pw2l,
                                      p1h, p1l, p2h, p2l, p3h, p3l);

  k_conv<IN_DIM><<<(N_NODES + 63) / 64, 512, 0, stream>>>(x, pw1h, pw1l, dinv, bufA);
  k_aggregate   <<<4096, 256, 0, stream>>>(bufA, offsets, csr_src, dinv, b1, bufB);
  k_conv<HID>   <<<(N_NODES + 63) / 64, 512, 0, stream>>>(bufB, pw2h, pw2l, dinv, bufA);
  k_aggregate   <<<4096, 256, 0, stream>>>(bufA, offsets, csr_src, dinv, b2, bufB);

  k_mlp<<<(N_NODES + 63) / 64, 512, 0, stream>>>(bufB, p1h, p1l, bf1, p2h, p2l, bf2,
                                                 p3h, p3l, bf3, out);
}